// Round 5
// baseline (737.369 us; speedup 1.0000x reference)
//
#include <hip/hip_runtime.h>
#include <math.h>

#define N_NODES 20000
#define E_EDGES 320000
#define DIN     256
#define HHD     512
#define HIDD    64
#define NHEADS  8
#define K1N     15000
#define K2N     11250

static inline int cdiv(long long a, long long b) { return (int)((a + b - 1) / b); }

__device__ __forceinline__ void atomicMaxF(float* addr, float val) {
  int* ai = (int*)addr;
  int old = __float_as_int(*addr);
  while (__int_as_float(old) < val) {
    int assumed = old;
    old = atomicCAS(ai, assumed, __float_as_int(val));
    if (old == assumed) break;
  }
}

__global__ void fill_i32(int* p, int v, int n) {
  int i = blockIdx.x * blockDim.x + threadIdx.x;
  if (i < n) p[i] = v;
}

// deg1[20000]=0, rank1[20000]=0, pools[1152]: [-inf x512, 0 x512, -inf x64, 0 x64]
__global__ void init_all(int* deg1, int* rank1, float* pools) {
  int i = blockIdx.x * blockDim.x + threadIdx.x;
  if (i < N_NODES) deg1[i] = 0;
  else if (i < 2 * N_NODES) rank1[i - N_NODES] = 0;
  else {
    int idx = i - 2 * N_NODES;
    if (idx < 1152)
      pools[idx] = (idx < 512 || (idx >= 1024 && idx < 1088)) ? -INFINITY : 0.f;
  }
}

// ---------------- dual-output GEMM, bank-conflict-free fragments ----------------
// Fragments split into 4-wide segments at stride BM/MSEG (BN/NSEG): lane stride
// 16B in LDS -> worst 2-way bank aliasing (free on CDNA4).
template<int BM, int BN, int BK, int TM, int TN>
__global__ __launch_bounds__(256) void gemm_dual(const float* __restrict__ A,
                                                 const int* __restrict__ perm,
                                                 const float* __restrict__ scalev,
                                                 const float* __restrict__ W1,
                                                 const float* __restrict__ W2,
                                                 float* __restrict__ C1,
                                                 float* __restrict__ C2,
                                                 int M, int Nc, int K) {
  constexpr int AS_LD = BM + 4;
  __shared__ float As[BK][AS_LD];
  __shared__ float Bs[BK][BN];
  constexpr int NTX = BN / TN;       // 16
  constexpr int MSEG = TM / 4;       // 1 or 2
  constexpr int NSEG = TN / 4;
  constexpr int MSTR = BM / MSEG;    // 64 (or BM)
  constexpr int NSTR = BN / NSEG;
  int tid = threadIdx.x;
  int tx = tid % NTX, ty = tid / NTX;
  int brow = blockIdx.y * BM, bcol0 = blockIdx.x * BN;
  const float* W = (bcol0 < Nc) ? W1 : W2;
  float* C = (bcol0 < Nc) ? C1 : C2;
  int bcol = (bcol0 < Nc) ? bcol0 : bcol0 - Nc;
  float acc[TM][TN] = {{0.f}};
  for (int k0 = 0; k0 < K; k0 += BK) {
    constexpr int AV = BM * BK / (4 * 256);
#pragma unroll
    for (int i = 0; i < AV; i++) {
      int idx = (tid + i * 256) * 4;
      int r = idx / BK, c = idx % BK;
      int gr = brow + r;
      float4 v = make_float4(0.f, 0.f, 0.f, 0.f);
      if (gr < M) {
        int ar = perm ? perm[gr] : gr;
        v = *(const float4*)(A + (size_t)ar * K + k0 + c);
        if (scalev) {
          float sc = scalev[ar];
          v.x *= sc; v.y *= sc; v.z *= sc; v.w *= sc;
        }
      }
      As[c][r] = v.x; As[c + 1][r] = v.y; As[c + 2][r] = v.z; As[c + 3][r] = v.w;
    }
    constexpr int BV = BK * BN / (4 * 256);
#pragma unroll
    for (int i = 0; i < BV; i++) {
      int idx = (tid + i * 256) * 4;
      int r = idx / BN, c = idx % BN;
      *(float4*)(&Bs[r][c]) = *(const float4*)(W + (size_t)(k0 + r) * Nc + bcol + c);
    }
    __syncthreads();
#pragma unroll
    for (int kk = 0; kk < BK; kk++) {
      float a[TM], b[TN];
#pragma unroll
      for (int s = 0; s < MSEG; s++)
        *(float4*)(&a[4 * s]) = *(const float4*)(&As[kk][ty * 4 + s * MSTR]);
#pragma unroll
      for (int s = 0; s < NSEG; s++)
        *(float4*)(&b[4 * s]) = *(const float4*)(&Bs[kk][tx * 4 + s * NSTR]);
#pragma unroll
      for (int u = 0; u < TM; u++)
#pragma unroll
        for (int v = 0; v < TN; v++) acc[u][v] += a[u] * b[v];
    }
    __syncthreads();
  }
#pragma unroll
  for (int su = 0; su < MSEG; su++)
#pragma unroll
    for (int u = 0; u < 4; u++) {
      int gr = brow + su * MSTR + ty * 4 + u;
      if (gr < M)
#pragma unroll
        for (int sv = 0; sv < NSEG; sv++)
          *(float4*)(C + (size_t)gr * Nc + bcol + sv * NSTR + tx * 4) =
              make_float4(acc[su * 4 + u][sv * 4], acc[su * 4 + u][sv * 4 + 1],
                          acc[su * 4 + u][sv * 4 + 2], acc[su * 4 + u][sv * 4 + 3]);
    }
}

// ---------------- CSR construction ----------------
__global__ void deg_count(const int* __restrict__ src, const int* __restrict__ dst,
                          const int* __restrict__ newid, int* __restrict__ deg,
                          int nloops) {
  int i = blockIdx.x * blockDim.x + threadIdx.x;
  if (i >= E_EDGES + nloops) return;
  int d;
  if (i < E_EDGES) {
    if (newid) {
      int s = newid[src[i]]; d = newid[dst[i]];
      if (s < 0 || d < 0) return;
    } else d = dst[i];
  } else d = i - E_EDGES;
  atomicAdd(&deg[d], 1);
}

// shuffle-based single-block exclusive scan; cursor may alias deg.
__global__ __launch_bounds__(1024) void scan_excl(const int* deg, int* rowptr,
                                                  int* cursor, int n) {
  __shared__ int wsum[16];
  __shared__ int carry;
  int tid = threadIdx.x, lane = tid & 63, wid = tid >> 6;
  if (tid == 0) { carry = 0; rowptr[0] = 0; }
  __syncthreads();
  for (int base = 0; base < n; base += 1024) {
    int v = (base + tid < n) ? deg[base + tid] : 0;
    int s = v;
#pragma unroll
    for (int off = 1; off < 64; off <<= 1) {
      int t = __shfl_up(s, off);
      if (lane >= off) s += t;
    }
    if (lane == 63) wsum[wid] = s;
    __syncthreads();
    if (wid == 0) {
      int w = (lane < 16) ? wsum[lane] : 0;
#pragma unroll
      for (int off = 1; off < 16; off <<= 1) {
        int t = __shfl_up(w, off);
        if (lane >= off) w += t;
      }
      if (lane < 16) wsum[lane] = w;
    }
    __syncthreads();
    int incl = s + (wid > 0 ? wsum[wid - 1] : 0) + carry;
    if (base + tid < n) { rowptr[base + tid + 1] = incl; cursor[base + tid] = incl - v; }
    __syncthreads();
    if (tid == 1023) carry = incl;
    __syncthreads();
  }
}

__global__ void csr_scatter(const int* __restrict__ src, const int* __restrict__ dst,
                            const int* __restrict__ newid, int* __restrict__ cursor,
                            int* __restrict__ csr_eid, int nloops) {
  int i = blockIdx.x * blockDim.x + threadIdx.x;
  if (i >= E_EDGES + nloops) return;
  int d;
  if (i < E_EDGES) {
    if (newid) {
      int s = newid[src[i]]; d = newid[dst[i]];
      if (s < 0 || d < 0) return;
    } else d = dst[i];
  } else d = i - E_EDGES;
  int pos = atomicAdd(&cursor[d], 1);
  csr_eid[pos] = i;
}

// ---------------- Stage 1 fused: GATv2 score + online softmax + aggregate + proj ----------------
__global__ __launch_bounds__(256) void gat1_fused(const int* __restrict__ rowptr,
                                                  const int* __restrict__ csr_eid,
                                                  const int* __restrict__ src,
                                                  const float* __restrict__ xl,
                                                  const float* __restrict__ xr,
                                                  const float* __restrict__ att,
                                                  const float* __restrict__ bias,
                                                  const float* __restrict__ pw,
                                                  float* __restrict__ out,
                                                  float* __restrict__ xls) {
  int lane = threadIdx.x & 63;
  long long t = (long long)blockIdx.x * blockDim.x + threadIdx.x;
  int d = (int)(t >> 6);
  if (d >= N_NODES) return;
  int base = lane * 8;
  float4 a0 = *(const float4*)(att + base);
  float4 a1 = *(const float4*)(att + base + 4);
  const float* xrp = xr + (size_t)d * HHD + base;
  float4 r0 = *(const float4*)(xrp);
  float4 r1 = *(const float4*)(xrp + 4);
  float m = -INFINITY, den = 0.f;
  float acc[8] = {0.f, 0.f, 0.f, 0.f, 0.f, 0.f, 0.f, 0.f};
  int b0 = rowptr[d], b1 = rowptr[d + 1];
  for (int j = b0; j < b1; j++) {
    int eid = csr_eid[j];
    int s = (eid < E_EDGES) ? src[eid] : eid - E_EDGES;
    const float* xlp = xl + (size_t)s * HHD + base;
    float4 v0 = *(const float4*)(xlp);
    float4 v1 = *(const float4*)(xlp + 4);
    float p, tv;
    tv = v0.x + r0.x; tv = tv > 0.f ? tv : 0.2f * tv; p  = tv * a0.x;
    tv = v0.y + r0.y; tv = tv > 0.f ? tv : 0.2f * tv; p += tv * a0.y;
    tv = v0.z + r0.z; tv = tv > 0.f ? tv : 0.2f * tv; p += tv * a0.z;
    tv = v0.w + r0.w; tv = tv > 0.f ? tv : 0.2f * tv; p += tv * a0.w;
    tv = v1.x + r1.x; tv = tv > 0.f ? tv : 0.2f * tv; p += tv * a1.x;
    tv = v1.y + r1.y; tv = tv > 0.f ? tv : 0.2f * tv; p += tv * a1.y;
    tv = v1.z + r1.z; tv = tv > 0.f ? tv : 0.2f * tv; p += tv * a1.z;
    tv = v1.w + r1.w; tv = tv > 0.f ? tv : 0.2f * tv; p += tv * a1.w;
    p += __shfl_xor(p, 1); p += __shfl_xor(p, 2); p += __shfl_xor(p, 4);
    float nm = fmaxf(m, p);
    float w  = __expf(p - nm);
    float sc = __expf(m - nm);
    den = den * sc + w;
    acc[0] = acc[0] * sc + w * v0.x;
    acc[1] = acc[1] * sc + w * v0.y;
    acc[2] = acc[2] * sc + w * v0.z;
    acc[3] = acc[3] * sc + w * v0.w;
    acc[4] = acc[4] * sc + w * v1.x;
    acc[5] = acc[5] * sc + w * v1.y;
    acc[6] = acc[6] * sc + w * v1.z;
    acc[7] = acc[7] * sc + w * v1.w;
    m = nm;
  }
  float inv = 1.f / den;
  float4 b0v = *(const float4*)(bias + base);
  float4 b1v = *(const float4*)(bias + base + 4);
  float o[8];
  o[0] = acc[0] * inv + b0v.x; o[1] = acc[1] * inv + b0v.y;
  o[2] = acc[2] * inv + b0v.z; o[3] = acc[3] * inv + b0v.w;
  o[4] = acc[4] * inv + b1v.x; o[5] = acc[5] * inv + b1v.y;
  o[6] = acc[6] * inv + b1v.z; o[7] = acc[7] * inv + b1v.w;
#pragma unroll
  for (int k = 0; k < 8; k++) o[k] = o[k] > 0.f ? o[k] : 0.f;
  float* op = out + (size_t)d * HHD + base;
  *(float4*)(op)     = make_float4(o[0], o[1], o[2], o[3]);
  *(float4*)(op + 4) = make_float4(o[4], o[5], o[6], o[7]);
  float4 w0 = *(const float4*)(pw + base);
  float4 w1 = *(const float4*)(pw + base + 4);
  float sdot = o[0]*w0.x + o[1]*w0.y + o[2]*w0.z + o[3]*w0.w
             + o[4]*w1.x + o[5]*w1.y + o[6]*w1.z + o[7]*w1.w;
#pragma unroll
  for (int off = 32; off > 0; off >>= 1) sdot += __shfl_xor(sdot, off);
  if (lane == 0) xls[d] = sdot;
}

// ---------------- Stage 2 fused: heads=1, dim 64 ----------------
__global__ __launch_bounds__(256) void gat2_fused(const int* __restrict__ rowptr,
                                                  const int* __restrict__ csr_eid,
                                                  const int* __restrict__ src,
                                                  const int* __restrict__ newid,
                                                  const float* __restrict__ xl,
                                                  const float* __restrict__ xr,
                                                  const float* __restrict__ att,
                                                  const float* __restrict__ bias,
                                                  const float* __restrict__ pw,
                                                  float* __restrict__ out,
                                                  float* __restrict__ xls, int n) {
  int lane = threadIdx.x & 63;
  long long t = (long long)blockIdx.x * blockDim.x + threadIdx.x;
  int d = (int)(t >> 6);
  if (d >= n) return;
  float av = att[lane];
  float rr = xr[(size_t)d * HIDD + lane];
  float m = -INFINITY, den = 0.f, acc = 0.f;
  int b0 = rowptr[d], b1 = rowptr[d + 1];
  for (int j = b0; j < b1; j++) {
    int eid = csr_eid[j];
    int s = (eid < E_EDGES) ? newid[src[eid]] : eid - E_EDGES;
    float v = xl[(size_t)s * HIDD + lane];
    float tv = v + rr; tv = tv > 0.f ? tv : 0.2f * tv;
    float p = tv * av;
#pragma unroll
    for (int off = 32; off > 0; off >>= 1) p += __shfl_xor(p, off);
    float nm = fmaxf(m, p);
    float w  = __expf(p - nm);
    float sc = __expf(m - nm);
    den = den * sc + w;
    acc = acc * sc + w * v;
    m = nm;
  }
  float o = acc / den + bias[lane];
  o = o > 0.f ? o : 0.f;
  out[(size_t)d * HIDD + lane] = o;
  float sdot = o * pw[lane];
#pragma unroll
  for (int off = 32; off > 0; off >>= 1) sdot += __shfl_xor(sdot, off);
  if (lane == 0) xls[d] = sdot;
}

// ---------------- pool scoring: single-pass online softmax + tanh ----------------
__global__ __launch_bounds__(256) void pool_score(const int* __restrict__ rowptr,
                                                  const int* __restrict__ csr_eid,
                                                  const int* __restrict__ src,
                                                  const int* __restrict__ newid_map,
                                                  const float* __restrict__ xls,
                                                  const float* __restrict__ asrc,
                                                  const float* __restrict__ adst,
                                                  const float* __restrict__ bias,
                                                  const float* __restrict__ sel,
                                                  float* __restrict__ score, int n) {
  int d = blockIdx.x * blockDim.x + threadIdx.x;
  if (d >= n) return;
  float as = asrc[0], ad = adst[0];
  float ar = xls[d] * ad;
  int b0 = rowptr[d], b1 = rowptr[d + 1];
  float m = -INFINITY, den = 0.f, num = 0.f;
  for (int j = b0; j < b1; j++) {
    int eid = csr_eid[j];
    int s = (eid < E_EDGES) ? (newid_map ? newid_map[src[eid]] : src[eid]) : eid - E_EDGES;
    float xs = xls[s];
    float e = xs * as + ar;
    e = e > 0.f ? e : 0.2f * e;
    float nm = fmaxf(m, e);
    float scv = __expf(m - nm);
    float ex = __expf(e - nm);
    den = den * scv + ex;
    num = num * scv + ex * xs;
    m = nm;
  }
  float attn = num / den + bias[0];
  float sv = sel[0];
  score[d] = tanhf(attn * sv / fabsf(sv));
}

// ---------------- top-k via 2D-grid rank counting ----------------
#define TK_CHUNK 512
__global__ __launch_bounds__(256) void topk_count(const float* __restrict__ score,
                                                  int* __restrict__ rank, int n) {
  __shared__ float sc[TK_CHUNK];
  int i = blockIdx.x * 256 + threadIdx.x;
  int base = blockIdx.y * TK_CHUNK;
  int cnt = min(TK_CHUNK, n - base);
  for (int j = threadIdx.x; j < cnt; j += 256) sc[j] = score[base + j];
  __syncthreads();
  if (i >= n) return;
  float si = score[i];
  int r = 0;
  for (int j = 0; j < cnt; j++) {
    float sj = sc[j];
    r += (sj > si) || ((sj == si) && ((base + j) < i));
  }
  if (r) atomicAdd(&rank[i], r);
}

__global__ void topk_assign(const int* __restrict__ rank, int* __restrict__ newid,
                            int* __restrict__ perm, int n, int k) {
  int i = blockIdx.x * blockDim.x + threadIdx.x;
  if (i < n) {
    int r = rank[i];
    newid[i] = (r < k) ? r : -1;
    if (r < k) perm[r] = i;
  }
}

// column max/sum over pooled rows, gathered via perm with score scaling
__global__ __launch_bounds__(256) void col_pool(const float* __restrict__ X,
                                                const int* __restrict__ perm,
                                                const float* __restrict__ scalev,
                                                int rows, int C,
                                                float* __restrict__ omax, float* __restrict__ osum) {
  int tid = threadIdx.x;
  float mx[2] = {-INFINITY, -INFINITY};
  float sm[2] = {0.f, 0.f};
  int nseg = (C + 255) / 256;
  int rpb = (rows + gridDim.x - 1) / gridDim.x;
  int rbeg = blockIdx.x * rpb;
  int rend = min(rows, rbeg + rpb);
  for (int r = rbeg; r < rend; r++) {
    int orow = perm[r];
    float sc = scalev[orow];
    const float* row = X + (size_t)orow * C;
    for (int sg = 0; sg < nseg; sg++) {
      int c = sg * 256 + tid;
      if (c < C) {
        float v = row[c] * sc;
        mx[sg] = fmaxf(mx[sg], v);
        sm[sg] += v;
      }
    }
  }
  if (rbeg < rend) {
    for (int sg = 0; sg < nseg; sg++) {
      int c = sg * 256 + tid;
      if (c < C) { atomicMaxF(&omax[c], mx[sg]); atomicAdd(&osum[c], sm[sg]); }
    }
  }
}

// ---------------- MLP head: z_build + layer1 fused; layers 2-4 fused ----------------
__global__ __launch_bounds__(256) void mlp_l1(const float* __restrict__ pools,
                                              const float* __restrict__ w1,
                                              const float* __restrict__ b1,
                                              float* __restrict__ z1out) {
  __shared__ float z[1024];
  __shared__ float red[16][17];
  int t = threadIdx.x;
  for (int i = t; i < 1024; i += 256) {
    float xv = (i < 512) ? pools[i] : pools[i] * (1.f / K1N);      // x1max | x1sum
    float gv = (i < 512) ? pools[1024 + (i & 63)] : pools[1088 + (i & 63)] * (1.f / K2N);
    z[i] = xv + gv;
  }
  __syncthreads();
  int jl = t & 15, ch = t >> 4;
  int j = blockIdx.x * 16 + jl;
  float p = 0.f;
  for (int k = ch * 64; k < ch * 64 + 64; k++) p += z[k] * w1[(size_t)k * 512 + j];
  red[ch][jl] = p;
  __syncthreads();
  if (t < 16) {
    float s = b1[blockIdx.x * 16 + t];
    for (int c = 0; c < 16; c++) s += red[c][t];
    z1out[blockIdx.x * 16 + t] = s > 0.f ? s : 0.f;
  }
}

__global__ __launch_bounds__(256) void mlp_tail(const float* __restrict__ z1,
                                                const float* __restrict__ w2, const float* __restrict__ b2,
                                                const float* __restrict__ w3, const float* __restrict__ b3,
                                                const float* __restrict__ w4, const float* __restrict__ b4,
                                                float* __restrict__ out) {
  __shared__ float z2[256], z3[128], lg[2];
  int t = threadIdx.x;
  {
    float acc = b2[t];
    for (int k = 0; k < 512; k++) acc += z1[k] * w2[(size_t)k * 256 + t];
    z2[t] = acc > 0.f ? acc : 0.f;
  }
  __syncthreads();
  if (t < 128) {
    float acc = b3[t];
    for (int k = 0; k < 256; k++) acc += z2[k] * w3[(size_t)k * 128 + t];
    z3[t] = acc > 0.f ? acc : 0.f;
  }
  __syncthreads();
  if (t < 2) {
    float acc = b4[t];
    for (int k = 0; k < 128; k++) acc += z3[k] * w4[2 * k + t];
    lg[t] = acc;
  }
  __syncthreads();
  if (t == 0) {
    float m = fmaxf(lg[0], lg[1]);
    float e0 = __expf(lg[0] - m), e1 = __expf(lg[1] - m);
    float s = e0 + e1;
    out[0] = lg[0]; out[1] = lg[1];
    out[2] = e0 / s; out[3] = e1 / s;
  }
}

extern "C" void kernel_launch(void* const* d_in, const int* in_sizes, int n_in,
                              void* d_out, int out_size, void* d_ws, size_t ws_size,
                              hipStream_t stream) {
  const float* x       = (const float*)d_in[0];
  const int*   ei      = (const int*)d_in[1];
  const float* g1_wl   = (const float*)d_in[2];
  const float* g1_wr   = (const float*)d_in[3];
  const float* g1_att  = (const float*)d_in[4];
  const float* g1_b    = (const float*)d_in[5];
  const float* p1_w    = (const float*)d_in[6];
  const float* p1_asrc = (const float*)d_in[7];
  const float* p1_adst = (const float*)d_in[8];
  const float* p1_b    = (const float*)d_in[9];
  const float* p1_sel  = (const float*)d_in[10];
  const float* g2_wl   = (const float*)d_in[11];
  const float* g2_wr   = (const float*)d_in[12];
  const float* g2_att  = (const float*)d_in[13];
  const float* g2_b    = (const float*)d_in[14];
  const float* p2_w    = (const float*)d_in[15];
  const float* p2_asrc = (const float*)d_in[16];
  const float* p2_adst = (const float*)d_in[17];
  const float* p2_b    = (const float*)d_in[18];
  const float* p2_sel  = (const float*)d_in[19];
  const float* l1_w    = (const float*)d_in[20];
  const float* l1_b    = (const float*)d_in[21];
  const float* l2_w    = (const float*)d_in[22];
  const float* l2_b    = (const float*)d_in[23];
  const float* l3_w    = (const float*)d_in[24];
  const float* l3_b    = (const float*)d_in[25];
  const float* l4_w    = (const float*)d_in[26];
  const float* l4_b    = (const float*)d_in[27];

  const int* src = ei;
  const int* dst = ei + E_EDGES;

  if (ws_size < (size_t)33440000 * 4) return;
  float* ws  = (float*)d_ws;
  float* xl1 = ws;                 // 10.24M
  float* xr1 = ws + 10240000;      // 10.24M; later arena2
  float* h1  = ws + 20480000;      // 10.24M
  float* aux = ws + 30720000;      // persistent small buffers

  int*   csr_eid1 = (int*)aux;               // 340000
  int*   rowptr1  = (int*)(aux + 340000);    // 20001
  int*   deg1     = (int*)(aux + 360064);    // 20000 (deg -> cursor)
  int*   rank1    = (int*)(aux + 380064);    // 20000
  int*   newid1   = (int*)(aux + 400064);    // 20000
  float* xls1     = aux + 420064;            // 20000
  float* scr1     = aux + 440064;            // 20000
  float* pools    = aux + 460064;            // 1152: x1max|x1sum|g2max|g2sum
  float* x1max    = pools;
  float* x1sum    = pools + 512;
  float* g2max    = pools + 1024;
  float* g2sum    = pools + 1088;
  int*   perm1    = (int*)(aux + 461248);    // 20000
  float* z1       = aux + 481248;            // 512

  float* a2 = xr1;                           // stage-2 arena (free after gat1_fused)
  float* xl2      = a2;                      // 960000
  float* xr2      = a2 + 960000;             // 960000
  float* h2       = a2 + 1920000;            // 960000
  int*   csr_eid2 = (int*)(a2 + 2880000);    // 335000
  int*   rowptr2  = (int*)(a2 + 3215000);    // 15001
  int*   deg2     = (int*)(a2 + 3230016);    // 15000  (deg2+rank2 contiguous)
  int*   rank2    = (int*)(a2 + 3245016);    // 15000
  int*   newid2   = (int*)(a2 + 3260016);    // 15000
  float* xls2     = a2 + 3275016;            // 15000
  float* scr2     = a2 + 3290016;            // 15000
  int*   perm2    = (int*)(a2 + 3305016);    // 15000

  dim3 b256(256);
  const int E1 = E_EDGES + N_NODES;   // 340000
  const int E2 = E_EDGES + K1N;       // 335000

  // ---- init + CSR1 ----
  init_all<<<cdiv(2 * N_NODES + 1152, 256), b256, 0, stream>>>(deg1, rank1, pools);
  deg_count<<<cdiv(E1, 256), b256, 0, stream>>>(src, dst, nullptr, deg1, N_NODES);
  scan_excl<<<1, 1024, 0, stream>>>(deg1, rowptr1, deg1, N_NODES);
  csr_scatter<<<cdiv(E1, 256), b256, 0, stream>>>(src, dst, nullptr, deg1, csr_eid1, N_NODES);

  // ---- Stage 1: fused dual GEMM (Wl|Wr) + fused GAT ----
  gemm_dual<128, 128, 16, 8, 8><<<dim3(2 * HHD / 128, cdiv(N_NODES, 128)), b256, 0, stream>>>(
      x, nullptr, nullptr, g1_wl, g1_wr, xl1, xr1, N_NODES, HHD, DIN);
  gat1_fused<<<cdiv((long long)N_NODES * 64, 256), b256, 0, stream>>>(
      rowptr1, csr_eid1, src, xl1, xr1, g1_att, g1_b, p1_w, h1, xls1);

  // ---- Pool 1 ----
  pool_score<<<cdiv(N_NODES, 256), b256, 0, stream>>>(rowptr1, csr_eid1, src, nullptr, xls1,
                                                      p1_asrc, p1_adst, p1_b, p1_sel, scr1, N_NODES);
  topk_count<<<dim3(cdiv(N_NODES, 256), cdiv(N_NODES, TK_CHUNK)), b256, 0, stream>>>(scr1, rank1, N_NODES);
  topk_assign<<<cdiv(N_NODES, 256), b256, 0, stream>>>(rank1, newid1, perm1, N_NODES, K1N);
  col_pool<<<128, b256, 0, stream>>>(h1, perm1, scr1, K1N, HHD, x1max, x1sum);

  // ---- CSR2 + Stage 2 (A rows gathered via perm1, scaled by scr1) ----
  fill_i32<<<cdiv(30000, 256), b256, 0, stream>>>(deg2, 0, 30000);  // deg2 + rank2
  deg_count<<<cdiv(E2, 256), b256, 0, stream>>>(src, dst, newid1, deg2, K1N);
  scan_excl<<<1, 1024, 0, stream>>>(deg2, rowptr2, deg2, K1N);
  csr_scatter<<<cdiv(E2, 256), b256, 0, stream>>>(src, dst, newid1, deg2, csr_eid2, K1N);

  gemm_dual<64, 64, 32, 4, 4><<<dim3(2 * HIDD / 64, cdiv(K1N, 64)), b256, 0, stream>>>(
      h1, perm1, scr1, g2_wl, g2_wr, xl2, xr2, K1N, HIDD, HHD);
  gat2_fused<<<cdiv((long long)K1N * 64, 256), b256, 0, stream>>>(
      rowptr2, csr_eid2, src, newid1, xl2, xr2, g2_att, g2_b, p2_w, h2, xls2, K1N);

  // ---- Pool 2 ----
  pool_score<<<cdiv(K1N, 256), b256, 0, stream>>>(rowptr2, csr_eid2, src, newid1, xls2,
                                                  p2_asrc, p2_adst, p2_b, p2_sel, scr2, K1N);
  topk_count<<<dim3(cdiv(K1N, 256), cdiv(K1N, TK_CHUNK)), b256, 0, stream>>>(scr2, rank2, K1N);
  topk_assign<<<cdiv(K1N, 256), b256, 0, stream>>>(rank2, newid2, perm2, K1N, K2N);
  col_pool<<<128, b256, 0, stream>>>(h2, perm2, scr2, K2N, HIDD, g2max, g2sum);

  // ---- MLP head ----
  mlp_l1<<<32, b256, 0, stream>>>(pools, l1_w, l1_b, z1);
  mlp_tail<<<1, b256, 0, stream>>>(z1, l2_w, l2_b, l3_w, l3_b, l4_w, l4_b, (float*)d_out);
}

// Round 6
// 681.228 us; speedup vs baseline: 1.0824x; 1.0824x over previous
//
#include <hip/hip_runtime.h>
#include <math.h>

#define N_NODES 20000
#define E_EDGES 320000
#define DIN     256
#define HHD     512
#define HIDD    64
#define NHEADS  8
#define K1N     15000
#define K2N     11250

typedef unsigned short u16;
typedef __attribute__((ext_vector_type(8))) short bf16x8;
typedef __attribute__((ext_vector_type(4))) float f32x4;

static inline int cdiv(long long a, long long b) { return (int)((a + b - 1) / b); }

__device__ __forceinline__ void atomicMaxF(float* addr, float val) {
  int* ai = (int*)addr;
  int old = __float_as_int(*addr);
  while (__int_as_float(old) < val) {
    int assumed = old;
    old = atomicCAS(ai, assumed, __float_as_int(val));
    if (old == assumed) break;
  }
}

__device__ __forceinline__ u16 f2bf(float x) {   // RNE f32 -> bf16 bits
  unsigned u = __float_as_uint(x);
  return (u16)((u + 0x7FFFu + ((u >> 16) & 1u)) >> 16);
}
__device__ __forceinline__ float bfval(u16 b) { return __uint_as_float(((unsigned)b) << 16); }

__global__ void fill_i32(int* p, int v, int n) {
  int i = blockIdx.x * blockDim.x + threadIdx.x;
  if (i < n) p[i] = v;
}

// deg1=0, rank1=0, pools[1152]: [-inf x512, 0 x512, -inf x64, 0 x64]
__global__ void init_all(int* deg1, int* rank1, float* pools) {
  int i = blockIdx.x * blockDim.x + threadIdx.x;
  if (i < N_NODES) deg1[i] = 0;
  else if (i < 2 * N_NODES) rank1[i - N_NODES] = 0;
  else {
    int idx = i - 2 * N_NODES;
    if (idx < 1152)
      pools[idx] = (idx < 512 || (idx >= 1024 && idx < 1088)) ? -INFINITY : 0.f;
  }
}

// ---------------- bf16 hi/lo split conversions ----------------
// A[M,K] f32 (optional perm-gather + scale) -> ah, al [M,K] bf16 bits
__global__ void conv_a(const float* __restrict__ A, const int* __restrict__ perm,
                       const float* __restrict__ scalev,
                       u16* __restrict__ ah, u16* __restrict__ al, int M, int K) {
  long long i = (long long)blockIdx.x * blockDim.x + threadIdx.x;
  long long e0 = i * 4;
  if (e0 >= (long long)M * K) return;
  int row = (int)(e0 / K), col = (int)(e0 % K);
  int ar = perm ? perm[row] : row;
  float4 v = *(const float4*)(A + (size_t)ar * K + col);
  if (scalev) { float s = scalev[ar]; v.x *= s; v.y *= s; v.z *= s; v.w *= s; }
  u16 h0 = f2bf(v.x), h1 = f2bf(v.y), h2 = f2bf(v.z), h3 = f2bf(v.w);
  u16 l0 = f2bf(v.x - bfval(h0)), l1 = f2bf(v.y - bfval(h1));
  u16 l2 = f2bf(v.z - bfval(h2)), l3 = f2bf(v.w - bfval(h3));
  uint2 hp, lp;
  hp.x = (unsigned)h0 | ((unsigned)h1 << 16); hp.y = (unsigned)h2 | ((unsigned)h3 << 16);
  lp.x = (unsigned)l0 | ((unsigned)l1 << 16); lp.y = (unsigned)l2 | ((unsigned)l3 << 16);
  *(uint2*)(ah + e0) = hp;
  *(uint2*)(al + e0) = lp;
}

// W = [W1 | W2], each [K, ncHalf] f32 -> wh, wl transposed [2*ncHalf][K] bf16 bits
__global__ void conv_w(const float* __restrict__ w1, const float* __restrict__ w2,
                       u16* __restrict__ wh, u16* __restrict__ wl, int ncHalf, int K) {
  int i = blockIdx.x * blockDim.x + threadIdx.x;
  int NT = 2 * ncHalf;
  if (i >= NT * K) return;
  int n = i % NT, k = i / NT;
  float v = (n < ncHalf) ? w1[(size_t)k * ncHalf + n] : w2[(size_t)k * ncHalf + (n - ncHalf)];
  u16 h = f2bf(v);
  u16 l = f2bf(v - bfval(h));
  wh[(size_t)n * K + k] = h;
  wl[(size_t)n * K + k] = l;
}

// ---------------- split-bf16 MFMA GEMM: C = A @ [W1|W2], 3-product compensation ----------------
// A: ah/al [M,K]; W: wh/wl [2*ncHalf][K] (n-major). 128x128 block tile, 4 waves of 64x64.
// c1 gets cols [0,ncHalf), c2 gets cols [ncHalf, 2*ncHalf). Row stride of c1/c2 = ncHalf.
__global__ __launch_bounds__(256) void gemm_bf16x3(const u16* __restrict__ ah,
                                                   const u16* __restrict__ al,
                                                   const u16* __restrict__ wh,
                                                   const u16* __restrict__ wl,
                                                   float* __restrict__ c1,
                                                   float* __restrict__ c2,
                                                   int M, int K, int ncHalf) {
  __shared__ u16 Ah[128][40], Al[128][40], Bh[128][40], Bl[128][40];  // 40 = 32 + 8 pad
  int tid = threadIdx.x;
  int lane = tid & 63, wid = tid >> 6;
  int wr = (wid >> 1) * 64, wc = (wid & 1) * 64;
  int brow = blockIdx.y * 128, bcol = blockIdx.x * 128;
  int fr = lane & 15, kg = lane >> 4;
  f32x4 acc[4][4];
#pragma unroll
  for (int i = 0; i < 4; i++)
#pragma unroll
    for (int j = 0; j < 4; j++) acc[i][j] = (f32x4){0.f, 0.f, 0.f, 0.f};

  for (int k0 = 0; k0 < K; k0 += 32) {
    // stage: 128 rows x 32 k of each of 4 buffers; 2 chunks/thread/buffer
#pragma unroll
    for (int i = 0; i < 2; i++) {
      int pos = tid + i * 256;        // 0..511
      int row = pos >> 2;             // 0..127
      int kc = (pos & 3) * 8;         // 0,8,16,24
      int gr = brow + row;
      float4 z = make_float4(0.f, 0.f, 0.f, 0.f);
      float4 vah = (gr < M) ? *(const float4*)(ah + (size_t)gr * K + k0 + kc) : z;
      float4 val = (gr < M) ? *(const float4*)(al + (size_t)gr * K + k0 + kc) : z;
      *(float4*)(&Ah[row][kc]) = vah;
      *(float4*)(&Al[row][kc]) = val;
      int gn = bcol + row;            // always < 2*ncHalf
      *(float4*)(&Bh[row][kc]) = *(const float4*)(wh + (size_t)gn * K + k0 + kc);
      *(float4*)(&Bl[row][kc]) = *(const float4*)(wl + (size_t)gn * K + k0 + kc);
    }
    __syncthreads();
    bf16x8 fa_h[4], fa_l[4], fb_h[4], fb_l[4];
#pragma unroll
    for (int t = 0; t < 4; t++) {
      fa_h[t] = *(const bf16x8*)(&Ah[wr + t * 16 + fr][kg * 8]);
      fa_l[t] = *(const bf16x8*)(&Al[wr + t * 16 + fr][kg * 8]);
      fb_h[t] = *(const bf16x8*)(&Bh[wc + t * 16 + fr][kg * 8]);
      fb_l[t] = *(const bf16x8*)(&Bl[wc + t * 16 + fr][kg * 8]);
    }
#pragma unroll
    for (int i = 0; i < 4; i++)
#pragma unroll
      for (int j = 0; j < 4; j++) {
        acc[i][j] = __builtin_amdgcn_mfma_f32_16x16x32_bf16(fa_h[i], fb_h[j], acc[i][j], 0, 0, 0);
        acc[i][j] = __builtin_amdgcn_mfma_f32_16x16x32_bf16(fa_h[i], fb_l[j], acc[i][j], 0, 0, 0);
        acc[i][j] = __builtin_amdgcn_mfma_f32_16x16x32_bf16(fa_l[i], fb_h[j], acc[i][j], 0, 0, 0);
      }
    __syncthreads();
  }
  // epilogue: C row = (lane>>4)*4 + reg, col = lane&15   [verified mapping]
#pragma unroll
  for (int i = 0; i < 4; i++) {
    int r0 = brow + wr + i * 16 + kg * 4;
#pragma unroll
    for (int j = 0; j < 4; j++) {
      int cg = bcol + wc + j * 16 + fr;
      float* cp = (cg < ncHalf) ? c1 : c2;
      int cc = (cg < ncHalf) ? cg : cg - ncHalf;
#pragma unroll
      for (int r = 0; r < 4; r++) {
        int gr = r0 + r;
        if (gr < M) cp[(size_t)gr * ncHalf + cc] = acc[i][j][r];
      }
    }
  }
}

// ---------------- CSR construction ----------------
__global__ void deg_count(const int* __restrict__ src, const int* __restrict__ dst,
                          const int* __restrict__ newid, int* __restrict__ deg,
                          int nloops) {
  int i = blockIdx.x * blockDim.x + threadIdx.x;
  if (i >= E_EDGES + nloops) return;
  int d;
  if (i < E_EDGES) {
    if (newid) {
      int s = newid[src[i]]; d = newid[dst[i]];
      if (s < 0 || d < 0) return;
    } else d = dst[i];
  } else d = i - E_EDGES;
  atomicAdd(&deg[d], 1);
}

// shuffle-based single-block exclusive scan; cursor may alias deg.
__global__ __launch_bounds__(1024) void scan_excl(const int* deg, int* rowptr,
                                                  int* cursor, int n) {
  __shared__ int wsum[16];
  __shared__ int carry;
  int tid = threadIdx.x, lane = tid & 63, wid = tid >> 6;
  if (tid == 0) { carry = 0; rowptr[0] = 0; }
  __syncthreads();
  for (int base = 0; base < n; base += 1024) {
    int v = (base + tid < n) ? deg[base + tid] : 0;
    int s = v;
#pragma unroll
    for (int off = 1; off < 64; off <<= 1) {
      int t = __shfl_up(s, off);
      if (lane >= off) s += t;
    }
    if (lane == 63) wsum[wid] = s;
    __syncthreads();
    if (wid == 0) {
      int w = (lane < 16) ? wsum[lane] : 0;
#pragma unroll
      for (int off = 1; off < 16; off <<= 1) {
        int t = __shfl_up(w, off);
        if (lane >= off) w += t;
      }
      if (lane < 16) wsum[lane] = w;
    }
    __syncthreads();
    int incl = s + (wid > 0 ? wsum[wid - 1] : 0) + carry;
    if (base + tid < n) { rowptr[base + tid + 1] = incl; cursor[base + tid] = incl - v; }
    __syncthreads();
    if (tid == 1023) carry = incl;
    __syncthreads();
  }
}

__global__ void csr_scatter(const int* __restrict__ src, const int* __restrict__ dst,
                            const int* __restrict__ newid, int* __restrict__ cursor,
                            int* __restrict__ csr_eid, int nloops) {
  int i = blockIdx.x * blockDim.x + threadIdx.x;
  if (i >= E_EDGES + nloops) return;
  int d;
  if (i < E_EDGES) {
    if (newid) {
      int s = newid[src[i]]; d = newid[dst[i]];
      if (s < 0 || d < 0) return;
    } else d = dst[i];
  } else d = i - E_EDGES;
  int pos = atomicAdd(&cursor[d], 1);
  csr_eid[pos] = i;
}

// ---------------- Stage 1 fused: GATv2 score + online softmax + aggregate + proj ----------------
__global__ __launch_bounds__(256) void gat1_fused(const int* __restrict__ rowptr,
                                                  const int* __restrict__ csr_eid,
                                                  const int* __restrict__ src,
                                                  const float* __restrict__ xl,
                                                  const float* __restrict__ xr,
                                                  const float* __restrict__ att,
                                                  const float* __restrict__ bias,
                                                  const float* __restrict__ pw,
                                                  float* __restrict__ out,
                                                  float* __restrict__ xls) {
  int lane = threadIdx.x & 63;
  long long t = (long long)blockIdx.x * blockDim.x + threadIdx.x;
  int d = (int)(t >> 6);
  if (d >= N_NODES) return;
  int base = lane * 8;
  float4 a0 = *(const float4*)(att + base);
  float4 a1 = *(const float4*)(att + base + 4);
  const float* xrp = xr + (size_t)d * HHD + base;
  float4 r0 = *(const float4*)(xrp);
  float4 r1 = *(const float4*)(xrp + 4);
  float m = -INFINITY, den = 0.f;
  float acc[8] = {0.f, 0.f, 0.f, 0.f, 0.f, 0.f, 0.f, 0.f};
  int b0 = rowptr[d], b1 = rowptr[d + 1];
  for (int j = b0; j < b1; j++) {
    int eid = csr_eid[j];
    int s = (eid < E_EDGES) ? src[eid] : eid - E_EDGES;
    const float* xlp = xl + (size_t)s * HHD + base;
    float4 v0 = *(const float4*)(xlp);
    float4 v1 = *(const float4*)(xlp + 4);
    float p, tv;
    tv = v0.x + r0.x; tv = tv > 0.f ? tv : 0.2f * tv; p  = tv * a0.x;
    tv = v0.y + r0.y; tv = tv > 0.f ? tv : 0.2f * tv; p += tv * a0.y;
    tv = v0.z + r0.z; tv = tv > 0.f ? tv : 0.2f * tv; p += tv * a0.z;
    tv = v0.w + r0.w; tv = tv > 0.f ? tv : 0.2f * tv; p += tv * a0.w;
    tv = v1.x + r1.x; tv = tv > 0.f ? tv : 0.2f * tv; p += tv * a1.x;
    tv = v1.y + r1.y; tv = tv > 0.f ? tv : 0.2f * tv; p += tv * a1.y;
    tv = v1.z + r1.z; tv = tv > 0.f ? tv : 0.2f * tv; p += tv * a1.z;
    tv = v1.w + r1.w; tv = tv > 0.f ? tv : 0.2f * tv; p += tv * a1.w;
    p += __shfl_xor(p, 1); p += __shfl_xor(p, 2); p += __shfl_xor(p, 4);
    float nm = fmaxf(m, p);
    float w  = __expf(p - nm);
    float sc = __expf(m - nm);
    den = den * sc + w;
    acc[0] = acc[0] * sc + w * v0.x;
    acc[1] = acc[1] * sc + w * v0.y;
    acc[2] = acc[2] * sc + w * v0.z;
    acc[3] = acc[3] * sc + w * v0.w;
    acc[4] = acc[4] * sc + w * v1.x;
    acc[5] = acc[5] * sc + w * v1.y;
    acc[6] = acc[6] * sc + w * v1.z;
    acc[7] = acc[7] * sc + w * v1.w;
    m = nm;
  }
  float inv = 1.f / den;
  float4 b0v = *(const float4*)(bias + base);
  float4 b1v = *(const float4*)(bias + base + 4);
  float o[8];
  o[0] = acc[0] * inv + b0v.x; o[1] = acc[1] * inv + b0v.y;
  o[2] = acc[2] * inv + b0v.z; o[3] = acc[3] * inv + b0v.w;
  o[4] = acc[4] * inv + b1v.x; o[5] = acc[5] * inv + b1v.y;
  o[6] = acc[6] * inv + b1v.z; o[7] = acc[7] * inv + b1v.w;
#pragma unroll
  for (int k = 0; k < 8; k++) o[k] = o[k] > 0.f ? o[k] : 0.f;
  float* op = out + (size_t)d * HHD + base;
  *(float4*)(op)     = make_float4(o[0], o[1], o[2], o[3]);
  *(float4*)(op + 4) = make_float4(o[4], o[5], o[6], o[7]);
  float4 w0 = *(const float4*)(pw + base);
  float4 w1 = *(const float4*)(pw + base + 4);
  float sdot = o[0]*w0.x + o[1]*w0.y + o[2]*w0.z + o[3]*w0.w
             + o[4]*w1.x + o[5]*w1.y + o[6]*w1.z + o[7]*w1.w;
#pragma unroll
  for (int off = 32; off > 0; off >>= 1) sdot += __shfl_xor(sdot, off);
  if (lane == 0) xls[d] = sdot;
}

// ---------------- Stage 2 fused: heads=1, dim 64 ----------------
__global__ __launch_bounds__(256) void gat2_fused(const int* __restrict__ rowptr,
                                                  const int* __restrict__ csr_eid,
                                                  const int* __restrict__ src,
                                                  const int* __restrict__ newid,
                                                  const float* __restrict__ xl,
                                                  const float* __restrict__ xr,
                                                  const float* __restrict__ att,
                                                  const float* __restrict__ bias,
                                                  const float* __restrict__ pw,
                                                  float* __restrict__ out,
                                                  float* __restrict__ xls, int n) {
  int lane = threadIdx.x & 63;
  long long t = (long long)blockIdx.x * blockDim.x + threadIdx.x;
  int d = (int)(t >> 6);
  if (d >= n) return;
  float av = att[lane];
  float rr = xr[(size_t)d * HIDD + lane];
  float m = -INFINITY, den = 0.f, acc = 0.f;
  int b0 = rowptr[d], b1 = rowptr[d + 1];
  for (int j = b0; j < b1; j++) {
    int eid = csr_eid[j];
    int s = (eid < E_EDGES) ? newid[src[eid]] : eid - E_EDGES;
    float v = xl[(size_t)s * HIDD + lane];
    float tv = v + rr; tv = tv > 0.f ? tv : 0.2f * tv;
    float p = tv * av;
#pragma unroll
    for (int off = 32; off > 0; off >>= 1) p += __shfl_xor(p, off);
    float nm = fmaxf(m, p);
    float w  = __expf(p - nm);
    float sc = __expf(m - nm);
    den = den * sc + w;
    acc = acc * sc + w * v;
    m = nm;
  }
  float o = acc / den + bias[lane];
  o = o > 0.f ? o : 0.f;
  out[(size_t)d * HIDD + lane] = o;
  float sdot = o * pw[lane];
#pragma unroll
  for (int off = 32; off > 0; off >>= 1) sdot += __shfl_xor(sdot, off);
  if (lane == 0) xls[d] = sdot;
}

// ---------------- pool scoring: single-pass online softmax + tanh ----------------
__global__ __launch_bounds__(256) void pool_score(const int* __restrict__ rowptr,
                                                  const int* __restrict__ csr_eid,
                                                  const int* __restrict__ src,
                                                  const int* __restrict__ newid_map,
                                                  const float* __restrict__ xls,
                                                  const float* __restrict__ asrc,
                                                  const float* __restrict__ adst,
                                                  const float* __restrict__ bias,
                                                  const float* __restrict__ sel,
                                                  float* __restrict__ score, int n) {
  int d = blockIdx.x * blockDim.x + threadIdx.x;
  if (d >= n) return;
  float as = asrc[0], ad = adst[0];
  float ar = xls[d] * ad;
  int b0 = rowptr[d], b1 = rowptr[d + 1];
  float m = -INFINITY, den = 0.f, num = 0.f;
  for (int j = b0; j < b1; j++) {
    int eid = csr_eid[j];
    int s = (eid < E_EDGES) ? (newid_map ? newid_map[src[eid]] : src[eid]) : eid - E_EDGES;
    float xs = xls[s];
    float e = xs * as + ar;
    e = e > 0.f ? e : 0.2f * e;
    float nm = fmaxf(m, e);
    float scv = __expf(m - nm);
    float ex = __expf(e - nm);
    den = den * scv + ex;
    num = num * scv + ex * xs;
    m = nm;
  }
  float attn = num / den + bias[0];
  float sv = sel[0];
  score[d] = tanhf(attn * sv / fabsf(sv));
}

// ---------------- top-k via 2D-grid rank counting ----------------
#define TK_CHUNK 512
__global__ __launch_bounds__(256) void topk_count(const float* __restrict__ score,
                                                  int* __restrict__ rank, int n) {
  __shared__ float sc[TK_CHUNK];
  int i = blockIdx.x * 256 + threadIdx.x;
  int base = blockIdx.y * TK_CHUNK;
  int cnt = min(TK_CHUNK, n - base);
  for (int j = threadIdx.x; j < cnt; j += 256) sc[j] = score[base + j];
  __syncthreads();
  if (i >= n) return;
  float si = score[i];
  int r = 0;
  for (int j = 0; j < cnt; j++) {
    float sj = sc[j];
    r += (sj > si) || ((sj == si) && ((base + j) < i));
  }
  if (r) atomicAdd(&rank[i], r);
}

__global__ void topk_assign(const int* __restrict__ rank, int* __restrict__ newid,
                            int* __restrict__ perm, int n, int k) {
  int i = blockIdx.x * blockDim.x + threadIdx.x;
  if (i < n) {
    int r = rank[i];
    newid[i] = (r < k) ? r : -1;
    if (r < k) perm[r] = i;
  }
}

// column max/sum over pooled rows, gathered via perm with score scaling
__global__ __launch_bounds__(256) void col_pool(const float* __restrict__ X,
                                                const int* __restrict__ perm,
                                                const float* __restrict__ scalev,
                                                int rows, int C,
                                                float* __restrict__ omax, float* __restrict__ osum) {
  int tid = threadIdx.x;
  float mx[2] = {-INFINITY, -INFINITY};
  float sm[2] = {0.f, 0.f};
  int nseg = (C + 255) / 256;
  int rpb = (rows + gridDim.x - 1) / gridDim.x;
  int rbeg = blockIdx.x * rpb;
  int rend = min(rows, rbeg + rpb);
  for (int r = rbeg; r < rend; r++) {
    int orow = perm[r];
    float sc = scalev[orow];
    const float* row = X + (size_t)orow * C;
    for (int sg = 0; sg < nseg; sg++) {
      int c = sg * 256 + tid;
      if (c < C) {
        float v = row[c] * sc;
        mx[sg] = fmaxf(mx[sg], v);
        sm[sg] += v;
      }
    }
  }
  if (rbeg < rend) {
    for (int sg = 0; sg < nseg; sg++) {
      int c = sg * 256 + tid;
      if (c < C) { atomicMaxF(&omax[c], mx[sg]); atomicAdd(&osum[c], sm[sg]); }
    }
  }
}

// ---------------- MLP head ----------------
__global__ __launch_bounds__(256) void mlp_l1(const float* __restrict__ pools,
                                              const float* __restrict__ w1,
                                              const float* __restrict__ b1,
                                              float* __restrict__ z1out) {
  __shared__ float z[1024];
  __shared__ float red[16][17];
  int t = threadIdx.x;
  for (int i = t; i < 1024; i += 256) {
    float xv = (i < 512) ? pools[i] : pools[i] * (1.f / K1N);
    float gv = (i < 512) ? pools[1024 + (i & 63)] : pools[1088 + (i & 63)] * (1.f / K2N);
    z[i] = xv + gv;
  }
  __syncthreads();
  int jl = t & 15, ch = t >> 4;
  int j = blockIdx.x * 16 + jl;
  float p = 0.f;
  for (int k = ch * 64; k < ch * 64 + 64; k++) p += z[k] * w1[(size_t)k * 512 + j];
  red[ch][jl] = p;
  __syncthreads();
  if (t < 16) {
    float s = b1[blockIdx.x * 16 + t];
    for (int c = 0; c < 16; c++) s += red[c][t];
    z1out[blockIdx.x * 16 + t] = s > 0.f ? s : 0.f;
  }
}

__global__ __launch_bounds__(256) void mlp_tail(const float* __restrict__ z1,
                                                const float* __restrict__ w2, const float* __restrict__ b2,
                                                const float* __restrict__ w3, const float* __restrict__ b3,
                                                const float* __restrict__ w4, const float* __restrict__ b4,
                                                float* __restrict__ out) {
  __shared__ float z2[256], z3[128], lg[2];
  int t = threadIdx.x;
  {
    float acc = b2[t];
    for (int k = 0; k < 512; k++) acc += z1[k] * w2[(size_t)k * 256 + t];
    z2[t] = acc > 0.f ? acc : 0.f;
  }
  __syncthreads();
  if (t < 128) {
    float acc = b3[t];
    for (int k = 0; k < 256; k++) acc += z2[k] * w3[(size_t)k * 128 + t];
    z3[t] = acc > 0.f ? acc : 0.f;
  }
  __syncthreads();
  if (t < 2) {
    float acc = b4[t];
    for (int k = 0; k < 128; k++) acc += z3[k] * w4[2 * k + t];
    lg[t] = acc;
  }
  __syncthreads();
  if (t == 0) {
    float m = fmaxf(lg[0], lg[1]);
    float e0 = __expf(lg[0] - m), e1 = __expf(lg[1] - m);
    float s = e0 + e1;
    out[0] = lg[0]; out[1] = lg[1];
    out[2] = e0 / s; out[3] = e1 / s;
  }
}

extern "C" void kernel_launch(void* const* d_in, const int* in_sizes, int n_in,
                              void* d_out, int out_size, void* d_ws, size_t ws_size,
                              hipStream_t stream) {
  const float* x       = (const float*)d_in[0];
  const int*   ei      = (const int*)d_in[1];
  const float* g1_wl   = (const float*)d_in[2];
  const float* g1_wr   = (const float*)d_in[3];
  const float* g1_att  = (const float*)d_in[4];
  const float* g1_b    = (const float*)d_in[5];
  const float* p1_w    = (const float*)d_in[6];
  const float* p1_asrc = (const float*)d_in[7];
  const float* p1_adst = (const float*)d_in[8];
  const float* p1_b    = (const float*)d_in[9];
  const float* p1_sel  = (const float*)d_in[10];
  const float* g2_wl   = (const float*)d_in[11];
  const float* g2_wr   = (const float*)d_in[12];
  const float* g2_att  = (const float*)d_in[13];
  const float* g2_b    = (const float*)d_in[14];
  const float* p2_w    = (const float*)d_in[15];
  const float* p2_asrc = (const float*)d_in[16];
  const float* p2_adst = (const float*)d_in[17];
  const float* p2_b    = (const float*)d_in[18];
  const float* p2_sel  = (const float*)d_in[19];
  const float* l1_w    = (const float*)d_in[20];
  const float* l1_b    = (const float*)d_in[21];
  const float* l2_w    = (const float*)d_in[22];
  const float* l2_b    = (const float*)d_in[23];
  const float* l3_w    = (const float*)d_in[24];
  const float* l3_b    = (const float*)d_in[25];
  const float* l4_w    = (const float*)d_in[26];
  const float* l4_b    = (const float*)d_in[27];

  const int* src = ei;
  const int* dst = ei + E_EDGES;

  if (ws_size < (size_t)33440000 * 4) return;
  float* ws  = (float*)d_ws;
  float* xl1 = ws;                 // 10.24M f32; stage-2 bf16 arena after gat1
  float* xr1 = ws + 10240000;      // 10.24M f32; arena2 after gat1
  float* h1  = ws + 20480000;      // 10.24M f32; stage-1 bf16 arena before gat1
  float* aux = ws + 30720000;      // persistent small buffers

  int*   csr_eid1 = (int*)aux;               // 340000
  int*   rowptr1  = (int*)(aux + 340000);    // 20001
  int*   deg1     = (int*)(aux + 360064);    // 20000 (deg -> cursor)
  int*   rank1    = (int*)(aux + 380064);    // 20000
  int*   newid1   = (int*)(aux + 400064);    // 20000
  float* xls1     = aux + 420064;            // 20000
  float* scr1     = aux + 440064;            // 20000
  float* pools    = aux + 460064;            // 1152: x1max|x1sum|g2max|g2sum
  float* x1max    = pools;
  float* x1sum    = pools + 512;
  float* g2max    = pools + 1024;
  float* g2sum    = pools + 1088;
  int*   perm1    = (int*)(aux + 461248);    // 20000
  float* z1       = aux + 481248;            // 512

  // stage-1 bf16 hi/lo arena (in h1 region; dead once gat1_fused writes h1)
  u16* ah1 = (u16*)h1;                 // 5,120,000 u16
  u16* al1 = ah1 + 5120000;            // 5,120,000
  u16* wh1 = al1 + 5120000;            // 262,144
  u16* wl1 = wh1 + 262144;             // 262,144  (total 10.76M u16 < 20.48M)

  // stage-2 bf16 hi/lo arena (in xl1 region; xl1 dead after gat1_fused)
  u16* ah2 = (u16*)xl1;                // 7,680,000 u16
  u16* al2 = ah2 + 7680000;            // 7,680,000
  u16* wh2 = al2 + 7680000;            // 65,536
  u16* wl2 = wh2 + 65536;              // 65,536   (total 15.49M u16 < 20.48M)

  float* a2 = xr1;                     // stage-2 f32 arena (xr1 dead after gat1_fused)
  float* xl2      = a2;                      // 960000
  float* xr2      = a2 + 960000;             // 960000
  float* h2       = a2 + 1920000;            // 960000
  int*   csr_eid2 = (int*)(a2 + 2880000);    // 335000
  int*   rowptr2  = (int*)(a2 + 3215000);    // 15001
  int*   deg2     = (int*)(a2 + 3230016);    // 15000 (deg2+rank2 contiguous)
  int*   rank2    = (int*)(a2 + 3245016);    // 15000
  int*   newid2   = (int*)(a2 + 3260016);    // 15000
  float* xls2     = a2 + 3275016;            // 15000
  float* scr2     = a2 + 3290016;            // 15000
  int*   perm2    = (int*)(a2 + 3305016);    // 15000

  dim3 b256(256);
  const int E1 = E_EDGES + N_NODES;   // 340000
  const int E2 = E_EDGES + K1N;       // 335000

  // ---- init + CSR1 ----
  init_all<<<cdiv(2 * N_NODES + 1152, 256), b256, 0, stream>>>(deg1, rank1, pools);
  deg_count<<<cdiv(E1, 256), b256, 0, stream>>>(src, dst, nullptr, deg1, N_NODES);
  scan_excl<<<1, 1024, 0, stream>>>(deg1, rowptr1, deg1, N_NODES);
  csr_scatter<<<cdiv(E1, 256), b256, 0, stream>>>(src, dst, nullptr, deg1, csr_eid1, N_NODES);

  // ---- Stage 1: bf16-split MFMA GEMM (Wl|Wr) + fused GAT ----
  conv_a<<<cdiv((long long)N_NODES * DIN / 4, 256), b256, 0, stream>>>(
      x, nullptr, nullptr, ah1, al1, N_NODES, DIN);
  conv_w<<<cdiv(2 * HHD * DIN, 256), b256, 0, stream>>>(g1_wl, g1_wr, wh1, wl1, HHD, DIN);
  gemm_bf16x3<<<dim3(2 * HHD / 128, cdiv(N_NODES, 128)), b256, 0, stream>>>(
      ah1, al1, wh1, wl1, xl1, xr1, N_NODES, DIN, HHD);
  gat1_fused<<<cdiv((long long)N_NODES * 64, 256), b256, 0, stream>>>(
      rowptr1, csr_eid1, src, xl1, xr1, g1_att, g1_b, p1_w, h1, xls1);

  // ---- Pool 1 ----
  pool_score<<<cdiv(N_NODES, 256), b256, 0, stream>>>(rowptr1, csr_eid1, src, nullptr, xls1,
                                                      p1_asrc, p1_adst, p1_b, p1_sel, scr1, N_NODES);
  topk_count<<<dim3(cdiv(N_NODES, 256), cdiv(N_NODES, TK_CHUNK)), b256, 0, stream>>>(scr1, rank1, N_NODES);
  topk_assign<<<cdiv(N_NODES, 256), b256, 0, stream>>>(rank1, newid1, perm1, N_NODES, K1N);
  col_pool<<<128, b256, 0, stream>>>(h1, perm1, scr1, K1N, HHD, x1max, x1sum);

  // ---- CSR2 + Stage 2 (A = h1 rows gathered via perm1, scaled by scr1) ----
  fill_i32<<<cdiv(30000, 256), b256, 0, stream>>>(deg2, 0, 30000);  // deg2 + rank2
  deg_count<<<cdiv(E2, 256), b256, 0, stream>>>(src, dst, newid1, deg2, K1N);
  scan_excl<<<1, 1024, 0, stream>>>(deg2, rowptr2, deg2, K1N);
  csr_scatter<<<cdiv(E2, 256), b256, 0, stream>>>(src, dst, newid1, deg2, csr_eid2, K1N);

  conv_a<<<cdiv((long long)K1N * HHD / 4, 256), b256, 0, stream>>>(
      h1, perm1, scr1, ah2, al2, K1N, HHD);
  conv_w<<<cdiv(2 * HIDD * HHD, 256), b256, 0, stream>>>(g2_wl, g2_wr, wh2, wl2, HIDD, HHD);
  gemm_bf16x3<<<dim3(2 * HIDD / 128, cdiv(K1N, 128)), b256, 0, stream>>>(
      ah2, al2, wh2, wl2, xl2, xr2, K1N, HHD, HIDD);
  gat2_fused<<<cdiv((long long)K1N * 64, 256), b256, 0, stream>>>(
      rowptr2, csr_eid2, src, newid1, xl2, xr2, g2_att, g2_b, p2_w, h2, xls2, K1N);

  // ---- Pool 2 ----
  pool_score<<<cdiv(K1N, 256), b256, 0, stream>>>(rowptr2, csr_eid2, src, newid1, xls2,
                                                  p2_asrc, p2_adst, p2_b, p2_sel, scr2, K1N);
  topk_count<<<dim3(cdiv(K1N, 256), cdiv(K1N, TK_CHUNK)), b256, 0, stream>>>(scr2, rank2, K1N);
  topk_assign<<<cdiv(K1N, 256), b256, 0, stream>>>(rank2, newid2, perm2, K1N, K2N);
  col_pool<<<128, b256, 0, stream>>>(h2, perm2, scr2, K2N, HIDD, g2max, g2sum);

  // ---- MLP head ----
  mlp_l1<<<32, b256, 0, stream>>>(pools, l1_w, l1_b, z1);
  mlp_tail<<<1, b256, 0, stream>>>(z1, l2_w, l2_b, l3_w, l3_b, l4_w, l4_b, (float*)d_out);
}

// Round 7
// 604.942 us; speedup vs baseline: 1.2189x; 1.1261x over previous
//
#include <hip/hip_runtime.h>
#include <math.h>

#define N_NODES 20000
#define E_EDGES 320000
#define DIN     256
#define HHD     512
#define HIDD    64
#define NHEADS  8
#define K1N     15000
#define K2N     11250

typedef unsigned short u16;
typedef __attribute__((ext_vector_type(8))) short bf16x8;
typedef __attribute__((ext_vector_type(4))) float f32x4;

static inline int cdiv(long long a, long long b) { return (int)((a + b - 1) / b); }

__device__ __forceinline__ void atomicMaxF(float* addr, float val) {
  int* ai = (int*)addr;
  int old = __float_as_int(*addr);
  while (__int_as_float(old) < val) {
    int assumed = old;
    old = atomicCAS(ai, assumed, __float_as_int(val));
    if (old == assumed) break;
  }
}

__device__ __forceinline__ u16 f2bf(float x) {   // RNE f32 -> bf16 bits
  unsigned u = __float_as_uint(x);
  return (u16)((u + 0x7FFFu + ((u >> 16) & 1u)) >> 16);
}
__device__ __forceinline__ float bfval(u16 b) { return __uint_as_float(((unsigned)b) << 16); }

__global__ void fill_i32(int* p, int v, int n) {
  int i = blockIdx.x * blockDim.x + threadIdx.x;
  if (i < n) p[i] = v;
}

// deg1=0, rank1=0, pools[1152]: [-inf x512, 0 x512, -inf x64, 0 x64]
__global__ void init_all(int* deg1, int* rank1, float* pools) {
  int i = blockIdx.x * blockDim.x + threadIdx.x;
  if (i < N_NODES) deg1[i] = 0;
  else if (i < 2 * N_NODES) rank1[i - N_NODES] = 0;
  else {
    int idx = i - 2 * N_NODES;
    if (idx < 1152)
      pools[idx] = (idx < 512 || (idx >= 1024 && idx < 1088)) ? -INFINITY : 0.f;
  }
}

// ---------------- fused bf16 hi/lo split conversion (A-part + W-part in one launch) ----------------
__global__ void conv_fused(const float* __restrict__ A, const int* __restrict__ perm,
                           const float* __restrict__ scalev,
                           u16* __restrict__ ah, u16* __restrict__ al, int M, int K,
                           const float* __restrict__ w1, const float* __restrict__ w2,
                           u16* __restrict__ wh, u16* __restrict__ wl, int ncHalf,
                           int aBlocks) {
  if ((int)blockIdx.x < aBlocks) {
    long long i = (long long)blockIdx.x * blockDim.x + threadIdx.x;
    long long e0 = i * 4;
    if (e0 >= (long long)M * K) return;
    int row = (int)(e0 / K), col = (int)(e0 % K);
    int ar = perm ? perm[row] : row;
    float4 v = *(const float4*)(A + (size_t)ar * K + col);
    if (scalev) { float s = scalev[ar]; v.x *= s; v.y *= s; v.z *= s; v.w *= s; }
    u16 h0 = f2bf(v.x), h1 = f2bf(v.y), h2 = f2bf(v.z), h3 = f2bf(v.w);
    u16 l0 = f2bf(v.x - bfval(h0)), l1 = f2bf(v.y - bfval(h1));
    u16 l2 = f2bf(v.z - bfval(h2)), l3 = f2bf(v.w - bfval(h3));
    uint2 hp, lp;
    hp.x = (unsigned)h0 | ((unsigned)h1 << 16); hp.y = (unsigned)h2 | ((unsigned)h3 << 16);
    lp.x = (unsigned)l0 | ((unsigned)l1 << 16); lp.y = (unsigned)l2 | ((unsigned)l3 << 16);
    *(uint2*)(ah + e0) = hp;
    *(uint2*)(al + e0) = lp;
  } else {
    int i = (blockIdx.x - aBlocks) * blockDim.x + threadIdx.x;
    int NT = 2 * ncHalf;
    if (i >= NT * K) return;
    int n = i % NT, k = i / NT;
    float v = (n < ncHalf) ? w1[(size_t)k * ncHalf + n] : w2[(size_t)k * ncHalf + (n - ncHalf)];
    u16 h = f2bf(v);
    u16 l = f2bf(v - bfval(h));
    wh[(size_t)n * K + k] = h;
    wl[(size_t)n * K + k] = l;
  }
}

// ---------------- split-bf16 MFMA GEMM: C = A @ [W1|W2], 3-product compensation ----------------
// BT = block tile (128 or 64). 4 waves in 2x2, each (BT/2)^2, F=BT/32 frags per dim.
template<int BT>
__global__ __launch_bounds__(256) void gemm_bf16x3(const u16* __restrict__ ah,
                                                   const u16* __restrict__ al,
                                                   const u16* __restrict__ wh,
                                                   const u16* __restrict__ wl,
                                                   float* __restrict__ c1,
                                                   float* __restrict__ c2,
                                                   int M, int K, int ncHalf) {
  constexpr int F = BT / 32;
  __shared__ u16 Ah[BT][40], Al[BT][40], Bh[BT][40], Bl[BT][40];
  int tid = threadIdx.x;
  int lane = tid & 63, wid = tid >> 6;
  int wr = (wid >> 1) * (BT / 2), wc = (wid & 1) * (BT / 2);
  int brow = blockIdx.y * BT, bcol = blockIdx.x * BT;
  int fr = lane & 15, kg = lane >> 4;
  f32x4 acc[F][F];
#pragma unroll
  for (int i = 0; i < F; i++)
#pragma unroll
    for (int j = 0; j < F; j++) acc[i][j] = (f32x4){0.f, 0.f, 0.f, 0.f};

  for (int k0 = 0; k0 < K; k0 += 32) {
    constexpr int ITER = (BT * 32) / (256 * 8);
#pragma unroll
    for (int i = 0; i < ITER; i++) {
      int pos = tid + i * 256;
      int row = pos >> 2;
      int kc = (pos & 3) * 8;
      int gr = brow + row;
      float4 z = make_float4(0.f, 0.f, 0.f, 0.f);
      float4 vah = (gr < M) ? *(const float4*)(ah + (size_t)gr * K + k0 + kc) : z;
      float4 val = (gr < M) ? *(const float4*)(al + (size_t)gr * K + k0 + kc) : z;
      *(float4*)(&Ah[row][kc]) = vah;
      *(float4*)(&Al[row][kc]) = val;
      int gn = bcol + row;
      *(float4*)(&Bh[row][kc]) = *(const float4*)(wh + (size_t)gn * K + k0 + kc);
      *(float4*)(&Bl[row][kc]) = *(const float4*)(wl + (size_t)gn * K + k0 + kc);
    }
    __syncthreads();
    bf16x8 fa_h[F], fa_l[F], fb_h[F], fb_l[F];
#pragma unroll
    for (int t = 0; t < F; t++) {
      fa_h[t] = *(const bf16x8*)(&Ah[wr + t * 16 + fr][kg * 8]);
      fa_l[t] = *(const bf16x8*)(&Al[wr + t * 16 + fr][kg * 8]);
      fb_h[t] = *(const bf16x8*)(&Bh[wc + t * 16 + fr][kg * 8]);
      fb_l[t] = *(const bf16x8*)(&Bl[wc + t * 16 + fr][kg * 8]);
    }
#pragma unroll
    for (int i = 0; i < F; i++)
#pragma unroll
      for (int j = 0; j < F; j++) {
        acc[i][j] = __builtin_amdgcn_mfma_f32_16x16x32_bf16(fa_h[i], fb_h[j], acc[i][j], 0, 0, 0);
        acc[i][j] = __builtin_amdgcn_mfma_f32_16x16x32_bf16(fa_h[i], fb_l[j], acc[i][j], 0, 0, 0);
        acc[i][j] = __builtin_amdgcn_mfma_f32_16x16x32_bf16(fa_l[i], fb_h[j], acc[i][j], 0, 0, 0);
      }
    __syncthreads();
  }
#pragma unroll
  for (int i = 0; i < F; i++) {
    int r0 = brow + wr + i * 16 + kg * 4;
#pragma unroll
    for (int j = 0; j < F; j++) {
      int cg = bcol + wc + j * 16 + fr;
      float* cp = (cg < ncHalf) ? c1 : c2;
      int cc = (cg < ncHalf) ? cg : cg - ncHalf;
#pragma unroll
      for (int r = 0; r < 4; r++) {
        int gr = r0 + r;
        if (gr < M) cp[(size_t)gr * ncHalf + cc] = acc[i][j][r];
      }
    }
  }
}

// ---------------- CSR construction (stores mapped source id directly) ----------------
__global__ void deg_count(const int* __restrict__ src, const int* __restrict__ dst,
                          const int* __restrict__ newid, int* __restrict__ deg,
                          int nloops) {
  int i = blockIdx.x * blockDim.x + threadIdx.x;
  if (i >= E_EDGES + nloops) return;
  int d;
  if (i < E_EDGES) {
    if (newid) {
      int s = newid[src[i]]; d = newid[dst[i]];
      if (s < 0 || d < 0) return;
    } else d = dst[i];
  } else d = i - E_EDGES;
  atomicAdd(&deg[d], 1);
}

// shuffle-based single-block exclusive scan; cursor may alias deg.
__global__ __launch_bounds__(1024) void scan_excl(const int* deg, int* rowptr,
                                                  int* cursor, int n) {
  __shared__ int wsum[16];
  __shared__ int carry;
  int tid = threadIdx.x, lane = tid & 63, wid = tid >> 6;
  if (tid == 0) { carry = 0; rowptr[0] = 0; }
  __syncthreads();
  for (int base = 0; base < n; base += 1024) {
    int v = (base + tid < n) ? deg[base + tid] : 0;
    int s = v;
#pragma unroll
    for (int off = 1; off < 64; off <<= 1) {
      int t = __shfl_up(s, off);
      if (lane >= off) s += t;
    }
    if (lane == 63) wsum[wid] = s;
    __syncthreads();
    if (wid == 0) {
      int w = (lane < 16) ? wsum[lane] : 0;
#pragma unroll
      for (int off = 1; off < 16; off <<= 1) {
        int t = __shfl_up(w, off);
        if (lane >= off) w += t;
      }
      if (lane < 16) wsum[lane] = w;
    }
    __syncthreads();
    int incl = s + (wid > 0 ? wsum[wid - 1] : 0) + carry;
    if (base + tid < n) { rowptr[base + tid + 1] = incl; cursor[base + tid] = incl - v; }
    __syncthreads();
    if (tid == 1023) carry = incl;
    __syncthreads();
  }
}

__global__ void csr_scatter(const int* __restrict__ src, const int* __restrict__ dst,
                            const int* __restrict__ newid, int* __restrict__ cursor,
                            int* __restrict__ csr_s, int nloops) {
  int i = blockIdx.x * blockDim.x + threadIdx.x;
  if (i >= E_EDGES + nloops) return;
  int s, d;
  if (i < E_EDGES) {
    s = src[i]; d = dst[i];
    if (newid) {
      s = newid[s]; d = newid[d];
      if (s < 0 || d < 0) return;
    }
  } else s = d = i - E_EDGES;
  int pos = atomicAdd(&cursor[d], 1);
  csr_s[pos] = s;
}

// ---------------- Stage 1 fused GAT, 2-deep software pipeline ----------------
__global__ __launch_bounds__(256) void gat1_fused(const int* __restrict__ rowptr,
                                                  const int* __restrict__ csr_s,
                                                  const float* __restrict__ xl,
                                                  const float* __restrict__ xr,
                                                  const float* __restrict__ att,
                                                  const float* __restrict__ bias,
                                                  const float* __restrict__ pw,
                                                  float* __restrict__ out,
                                                  float* __restrict__ xls) {
  int lane = threadIdx.x & 63;
  long long t = (long long)blockIdx.x * blockDim.x + threadIdx.x;
  int d = (int)(t >> 6);
  if (d >= N_NODES) return;
  int base = lane * 8;
  float4 a0 = *(const float4*)(att + base);
  float4 a1 = *(const float4*)(att + base + 4);
  const float* xrp = xr + (size_t)d * HHD + base;
  float4 r0 = *(const float4*)(xrp);
  float4 r1 = *(const float4*)(xrp + 4);
  float m = -INFINITY, den = 0.f;
  float acc[8] = {0.f, 0.f, 0.f, 0.f, 0.f, 0.f, 0.f, 0.f};
  int b0 = rowptr[d];
  int cnt = rowptr[d + 1] - b0;
  const int* sp = csr_s + b0;

  auto online = [&](float4 v0, float4 v1) {
    float p, tv;
    tv = v0.x + r0.x; tv = tv > 0.f ? tv : 0.2f * tv; p  = tv * a0.x;
    tv = v0.y + r0.y; tv = tv > 0.f ? tv : 0.2f * tv; p += tv * a0.y;
    tv = v0.z + r0.z; tv = tv > 0.f ? tv : 0.2f * tv; p += tv * a0.z;
    tv = v0.w + r0.w; tv = tv > 0.f ? tv : 0.2f * tv; p += tv * a0.w;
    tv = v1.x + r1.x; tv = tv > 0.f ? tv : 0.2f * tv; p += tv * a1.x;
    tv = v1.y + r1.y; tv = tv > 0.f ? tv : 0.2f * tv; p += tv * a1.y;
    tv = v1.z + r1.z; tv = tv > 0.f ? tv : 0.2f * tv; p += tv * a1.z;
    tv = v1.w + r1.w; tv = tv > 0.f ? tv : 0.2f * tv; p += tv * a1.w;
    p += __shfl_xor(p, 1); p += __shfl_xor(p, 2); p += __shfl_xor(p, 4);
    float nm = fmaxf(m, p);
    float w  = __expf(p - nm);
    float sc = __expf(m - nm);
    den = den * sc + w;
    acc[0] = acc[0] * sc + w * v0.x;
    acc[1] = acc[1] * sc + w * v0.y;
    acc[2] = acc[2] * sc + w * v0.z;
    acc[3] = acc[3] * sc + w * v0.w;
    acc[4] = acc[4] * sc + w * v1.x;
    acc[5] = acc[5] * sc + w * v1.y;
    acc[6] = acc[6] * sc + w * v1.z;
    acc[7] = acc[7] * sc + w * v1.w;
    m = nm;
  };

  // preload edges 0 and 1 (cnt >= 1 always: self-loop)
  float4 A0, A1, B0, B1;
  {
    const float* p0 = xl + (size_t)sp[0] * HHD + base;
    A0 = *(const float4*)p0; A1 = *(const float4*)(p0 + 4);
  }
  B0 = make_float4(0.f, 0.f, 0.f, 0.f); B1 = B0;
  if (cnt > 1) {
    const float* p1 = xl + (size_t)sp[1] * HHD + base;
    B0 = *(const float4*)p1; B1 = *(const float4*)(p1 + 4);
  }
  int j = 0;
  for (; j + 2 <= cnt; j += 2) {
    float4 v0 = A0, v1 = A1;
    if (j + 2 < cnt) {
      const float* pn = xl + (size_t)sp[j + 2] * HHD + base;
      A0 = *(const float4*)pn; A1 = *(const float4*)(pn + 4);
    }
    online(v0, v1);
    v0 = B0; v1 = B1;
    if (j + 3 < cnt) {
      const float* pn = xl + (size_t)sp[j + 3] * HHD + base;
      B0 = *(const float4*)pn; B1 = *(const float4*)(pn + 4);
    }
    online(v0, v1);
  }
  if (j < cnt) online(A0, A1);

  float inv = 1.f / den;
  float4 b0v = *(const float4*)(bias + base);
  float4 b1v = *(const float4*)(bias + base + 4);
  float o[8];
  o[0] = acc[0] * inv + b0v.x; o[1] = acc[1] * inv + b0v.y;
  o[2] = acc[2] * inv + b0v.z; o[3] = acc[3] * inv + b0v.w;
  o[4] = acc[4] * inv + b1v.x; o[5] = acc[5] * inv + b1v.y;
  o[6] = acc[6] * inv + b1v.z; o[7] = acc[7] * inv + b1v.w;
#pragma unroll
  for (int k = 0; k < 8; k++) o[k] = o[k] > 0.f ? o[k] : 0.f;
  float* op = out + (size_t)d * HHD + base;
  *(float4*)(op)     = make_float4(o[0], o[1], o[2], o[3]);
  *(float4*)(op + 4) = make_float4(o[4], o[5], o[6], o[7]);
  float4 w0 = *(const float4*)(pw + base);
  float4 w1 = *(const float4*)(pw + base + 4);
  float sdot = o[0]*w0.x + o[1]*w0.y + o[2]*w0.z + o[3]*w0.w
             + o[4]*w1.x + o[5]*w1.y + o[6]*w1.z + o[7]*w1.w;
#pragma unroll
  for (int off = 32; off > 0; off >>= 1) sdot += __shfl_xor(sdot, off);
  if (lane == 0) xls[d] = sdot;
}

// ---------------- Stage 2 fused GAT, 2-deep pipeline ----------------
__global__ __launch_bounds__(256) void gat2_fused(const int* __restrict__ rowptr,
                                                  const int* __restrict__ csr_s,
                                                  const float* __restrict__ xl,
                                                  const float* __restrict__ xr,
                                                  const float* __restrict__ att,
                                                  const float* __restrict__ bias,
                                                  const float* __restrict__ pw,
                                                  float* __restrict__ out,
                                                  float* __restrict__ xls, int n) {
  int lane = threadIdx.x & 63;
  long long t = (long long)blockIdx.x * blockDim.x + threadIdx.x;
  int d = (int)(t >> 6);
  if (d >= n) return;
  float av = att[lane];
  float rr = xr[(size_t)d * HIDD + lane];
  float m = -INFINITY, den = 0.f, acc = 0.f;
  int b0 = rowptr[d];
  int cnt = rowptr[d + 1] - b0;
  const int* sp = csr_s + b0;

  auto online = [&](float v) {
    float tv = v + rr; tv = tv > 0.f ? tv : 0.2f * tv;
    float p = tv * av;
#pragma unroll
    for (int off = 32; off > 0; off >>= 1) p += __shfl_xor(p, off);
    float nm = fmaxf(m, p);
    float w  = __expf(p - nm);
    float sc = __expf(m - nm);
    den = den * sc + w;
    acc = acc * sc + w * v;
    m = nm;
  };

  float vA = xl[(size_t)sp[0] * HIDD + lane];
  float vB = (cnt > 1) ? xl[(size_t)sp[1] * HIDD + lane] : 0.f;
  int j = 0;
  for (; j + 2 <= cnt; j += 2) {
    float v = vA;
    if (j + 2 < cnt) vA = xl[(size_t)sp[j + 2] * HIDD + lane];
    online(v);
    v = vB;
    if (j + 3 < cnt) vB = xl[(size_t)sp[j + 3] * HIDD + lane];
    online(v);
  }
  if (j < cnt) online(vA);

  float o = acc / den + bias[lane];
  o = o > 0.f ? o : 0.f;
  out[(size_t)d * HIDD + lane] = o;
  float sdot = o * pw[lane];
#pragma unroll
  for (int off = 32; off > 0; off >>= 1) sdot += __shfl_xor(sdot, off);
  if (lane == 0) xls[d] = sdot;
}

// ---------------- pool scoring: online softmax + tanh, 2-deep prefetch ----------------
__global__ __launch_bounds__(256) void pool_score(const int* __restrict__ rowptr,
                                                  const int* __restrict__ csr_s,
                                                  const float* __restrict__ xls,
                                                  const float* __restrict__ asrc,
                                                  const float* __restrict__ adst,
                                                  const float* __restrict__ bias,
                                                  const float* __restrict__ sel,
                                                  float* __restrict__ score, int n) {
  int d = blockIdx.x * blockDim.x + threadIdx.x;
  if (d >= n) return;
  float as = asrc[0], ad = adst[0];
  float ar = xls[d] * ad;
  int b0 = rowptr[d];
  int cnt = rowptr[d + 1] - b0;
  const int* sp = csr_s + b0;
  float m = -INFINITY, den = 0.f, num = 0.f;
  auto upd = [&](float xs) {
    float e = xs * as + ar;
    e = e > 0.f ? e : 0.2f * e;
    float nm = fmaxf(m, e);
    float scv = __expf(m - nm);
    float ex = __expf(e - nm);
    den = den * scv + ex;
    num = num * scv + ex * xs;
    m = nm;
  };
  float xA = xls[sp[0]];
  float xB = (cnt > 1) ? xls[sp[1]] : 0.f;
  int j = 0;
  for (; j + 2 <= cnt; j += 2) {
    float x1 = xA;
    if (j + 2 < cnt) xA = xls[sp[j + 2]];
    upd(x1);
    float x2 = xB;
    if (j + 3 < cnt) xB = xls[sp[j + 3]];
    upd(x2);
  }
  if (j < cnt) upd(xA);
  float attn = num / den + bias[0];
  float sv = sel[0];
  score[d] = tanhf(attn * sv / fabsf(sv));
}

// ---------------- top-k via 2D-grid rank counting ----------------
#define TK_CHUNK 512
__global__ __launch_bounds__(256) void topk_count(const float* __restrict__ score,
                                                  int* __restrict__ rank, int n) {
  __shared__ float sc[TK_CHUNK];
  int i = blockIdx.x * 256 + threadIdx.x;
  int base = blockIdx.y * TK_CHUNK;
  int cnt = min(TK_CHUNK, n - base);
  for (int j = threadIdx.x; j < cnt; j += 256) sc[j] = score[base + j];
  __syncthreads();
  if (i >= n) return;
  float si = score[i];
  int r = 0;
  for (int j = 0; j < cnt; j++) {
    float sj = sc[j];
    r += (sj > si) || ((sj == si) && ((base + j) < i));
  }
  if (r) atomicAdd(&rank[i], r);
}

__global__ void topk_assign(const int* __restrict__ rank, int* __restrict__ newid,
                            int* __restrict__ perm, int n, int k) {
  int i = blockIdx.x * blockDim.x + threadIdx.x;
  if (i < n) {
    int r = rank[i];
    newid[i] = (r < k) ? r : -1;
    if (r < k) perm[r] = i;
  }
}

// column max/sum over pooled rows, gathered via perm with score scaling
__global__ __launch_bounds__(256) void col_pool(const float* __restrict__ X,
                                                const int* __restrict__ perm,
                                                const float* __restrict__ scalev,
                                                int rows, int C,
                                                float* __restrict__ omax, float* __restrict__ osum) {
  int tid = threadIdx.x;
  float mx[2] = {-INFINITY, -INFINITY};
  float sm[2] = {0.f, 0.f};
  int nseg = (C + 255) / 256;
  int rpb = (rows + gridDim.x - 1) / gridDim.x;
  int rbeg = blockIdx.x * rpb;
  int rend = min(rows, rbeg + rpb);
  for (int r = rbeg; r < rend; r++) {
    int orow = perm[r];
    float sc = scalev[orow];
    const float* row = X + (size_t)orow * C;
    for (int sg = 0; sg < nseg; sg++) {
      int c = sg * 256 + tid;
      if (c < C) {
        float v = row[c] * sc;
        mx[sg] = fmaxf(mx[sg], v);
        sm[sg] += v;
      }
    }
  }
  if (rbeg < rend) {
    for (int sg = 0; sg < nseg; sg++) {
      int c = sg * 256 + tid;
      if (c < C) { atomicMaxF(&omax[c], mx[sg]); atomicAdd(&osum[c], sm[sg]); }
    }
  }
}

// ---------------- MLP head ----------------
__global__ __launch_bounds__(256) void mlp_l1(const float* __restrict__ pools,
                                              const float* __restrict__ w1,
                                              const float* __restrict__ b1,
                                              float* __restrict__ z1out) {
  __shared__ float z[1024];
  __shared__ float red[16][17];
  int t = threadIdx.x;
  for (int i = t; i < 1024; i += 256) {
    float xv = (i < 512) ? pools[i] : pools[i] * (1.f / K1N);
    float gv = (i < 512) ? pools[1024 + (i & 63)] : pools[1088 + (i & 63)] * (1.f / K2N);
    z[i] = xv + gv;
  }
  __syncthreads();
  int jl = t & 15, ch = t >> 4;
  int j = blockIdx.x * 16 + jl;
  float p = 0.f;
  for (int k = ch * 64; k < ch * 64 + 64; k++) p += z[k] * w1[(size_t)k * 512 + j];
  red[ch][jl] = p;
  __syncthreads();
  if (t < 16) {
    float s = b1[blockIdx.x * 16 + t];
    for (int c = 0; c < 16; c++) s += red[c][t];
    z1out[blockIdx.x * 16 + t] = s > 0.f ? s : 0.f;
  }
}

__global__ __launch_bounds__(256) void mlp_tail(const float* __restrict__ z1,
                                                const float* __restrict__ w2, const float* __restrict__ b2,
                                                const float* __restrict__ w3, const float* __restrict__ b3,
                                                const float* __restrict__ w4, const float* __restrict__ b4,
                                                float* __restrict__ out) {
  __shared__ float z2[256], z3[128], lg[2];
  int t = threadIdx.x;
  {
    float acc = b2[t];
    for (int k = 0; k < 512; k++) acc += z1[k] * w2[(size_t)k * 256 + t];
    z2[t] = acc > 0.f ? acc : 0.f;
  }
  __syncthreads();
  if (t < 128) {
    float acc = b3[t];
    for (int k = 0; k < 256; k++) acc += z2[k] * w3[(size_t)k * 128 + t];
    z3[t] = acc > 0.f ? acc : 0.f;
  }
  __syncthreads();
  if (t < 2) {
    float acc = b4[t];
    for (int k = 0; k < 128; k++) acc += z3[k] * w4[2 * k + t];
    lg[t] = acc;
  }
  __syncthreads();
  if (t == 0) {
    float m = fmaxf(lg[0], lg[1]);
    float e0 = __expf(lg[0] - m), e1 = __expf(lg[1] - m);
    float s = e0 + e1;
    out[0] = lg[0]; out[1] = lg[1];
    out[2] = e0 / s; out[3] = e1 / s;
  }
}

extern "C" void kernel_launch(void* const* d_in, const int* in_sizes, int n_in,
                              void* d_out, int out_size, void* d_ws, size_t ws_size,
                              hipStream_t stream) {
  const float* x       = (const float*)d_in[0];
  const int*   ei      = (const int*)d_in[1];
  const float* g1_wl   = (const float*)d_in[2];
  const float* g1_wr   = (const float*)d_in[3];
  const float* g1_att  = (const float*)d_in[4];
  const float* g1_b    = (const float*)d_in[5];
  const float* p1_w    = (const float*)d_in[6];
  const float* p1_asrc = (const float*)d_in[7];
  const float* p1_adst = (const float*)d_in[8];
  const float* p1_b    = (const float*)d_in[9];
  const float* p1_sel  = (const float*)d_in[10];
  const float* g2_wl   = (const float*)d_in[11];
  const float* g2_wr   = (const float*)d_in[12];
  const float* g2_att  = (const float*)d_in[13];
  const float* g2_b    = (const float*)d_in[14];
  const float* p2_w    = (const float*)d_in[15];
  const float* p2_asrc = (const float*)d_in[16];
  const float* p2_adst = (const float*)d_in[17];
  const float* p2_b    = (const float*)d_in[18];
  const float* p2_sel  = (const float*)d_in[19];
  const float* l1_w    = (const float*)d_in[20];
  const float* l1_b    = (const float*)d_in[21];
  const float* l2_w    = (const float*)d_in[22];
  const float* l2_b    = (const float*)d_in[23];
  const float* l3_w    = (const float*)d_in[24];
  const float* l3_b    = (const float*)d_in[25];
  const float* l4_w    = (const float*)d_in[26];
  const float* l4_b    = (const float*)d_in[27];

  const int* src = ei;
  const int* dst = ei + E_EDGES;

  if (ws_size < (size_t)33440000 * 4) return;
  float* ws  = (float*)d_ws;
  float* xl1 = ws;                 // 10.24M f32; stage-2 bf16 arena after gat1
  float* xr1 = ws + 10240000;      // 10.24M f32; arena2 after gat1
  float* h1  = ws + 20480000;      // 10.24M f32; stage-1 bf16 arena before gat1
  float* aux = ws + 30720000;      // persistent small buffers

  int*   csr_s1   = (int*)aux;               // 340000
  int*   rowptr1  = (int*)(aux + 340000);    // 20001
  int*   deg1     = (int*)(aux + 360064);    // 20000 (deg -> cursor)
  int*   rank1    = (int*)(aux + 380064);    // 20000
  int*   newid1   = (int*)(aux + 400064);    // 20000
  float* xls1     = aux + 420064;            // 20000
  float* scr1     = aux + 440064;            // 20000
  float* pools    = aux + 460064;            // 1152: x1max|x1sum|g2max|g2sum
  float* x1max    = pools;
  float* x1sum    = pools + 512;
  float* g2max    = pools + 1024;
  float* g2sum    = pools + 1088;
  int*   perm1    = (int*)(aux + 461248);    // 20000
  float* z1       = aux + 481248;            // 512

  // stage-1 bf16 hi/lo arena (in h1 region; dead once gat1_fused writes h1)
  u16* ah1 = (u16*)h1;                 // 5,120,000 u16
  u16* al1 = ah1 + 5120000;            // 5,120,000
  u16* wh1 = al1 + 5120000;            // 262,144
  u16* wl1 = wh1 + 262144;             // 262,144

  // stage-2 bf16 hi/lo arena (in xl1 region; xl1 dead after gat1_fused)
  u16* ah2 = (u16*)xl1;                // 7,680,000 u16
  u16* al2 = ah2 + 7680000;            // 7,680,000
  u16* wh2 = al2 + 7680000;            // 65,536
  u16* wl2 = wh2 + 65536;              // 65,536

  float* a2 = xr1;                     // stage-2 f32 arena (xr1 dead after gat1_fused)
  float* xl2      = a2;                      // 960000
  float* xr2      = a2 + 960000;             // 960000
  float* h2       = a2 + 1920000;            // 960000
  int*   csr_s2   = (int*)(a2 + 2880000);    // 335000
  int*   rowptr2  = (int*)(a2 + 3215000);    // 15001
  int*   deg2     = (int*)(a2 + 3230016);    // 15000 (deg2+rank2 contiguous)
  int*   rank2    = (int*)(a2 + 3245016);    // 15000
  int*   newid2   = (int*)(a2 + 3260016);    // 15000
  float* xls2     = a2 + 3275016;            // 15000
  float* scr2     = a2 + 3290016;            // 15000
  int*   perm2    = (int*)(a2 + 3305016);    // 15000

  dim3 b256(256);
  const int E1 = E_EDGES + N_NODES;   // 340000
  const int E2 = E_EDGES + K1N;       // 335000

  // ---- init + CSR1 ----
  init_all<<<cdiv(2 * N_NODES + 1152, 256), b256, 0, stream>>>(deg1, rank1, pools);
  deg_count<<<cdiv(E1, 256), b256, 0, stream>>>(src, dst, nullptr, deg1, N_NODES);
  scan_excl<<<1, 1024, 0, stream>>>(deg1, rowptr1, deg1, N_NODES);
  csr_scatter<<<cdiv(E1, 256), b256, 0, stream>>>(src, dst, nullptr, deg1, csr_s1, N_NODES);

  // ---- Stage 1: conv + bf16-split MFMA GEMM (Wl|Wr) + fused GAT ----
  {
    int aBlocks = cdiv((long long)N_NODES * DIN / 4, 256);
    int wBlocks = cdiv(2 * HHD * DIN, 256);
    conv_fused<<<aBlocks + wBlocks, b256, 0, stream>>>(
        x, nullptr, nullptr, ah1, al1, N_NODES, DIN, g1_wl, g1_wr, wh1, wl1, HHD, aBlocks);
  }
  gemm_bf16x3<128><<<dim3(2 * HHD / 128, cdiv(N_NODES, 128)), b256, 0, stream>>>(
      ah1, al1, wh1, wl1, xl1, xr1, N_NODES, DIN, HHD);
  gat1_fused<<<cdiv((long long)N_NODES * 64, 256), b256, 0, stream>>>(
      rowptr1, csr_s1, xl1, xr1, g1_att, g1_b, p1_w, h1, xls1);

  // ---- Pool 1 ----
  pool_score<<<cdiv(N_NODES, 256), b256, 0, stream>>>(rowptr1, csr_s1, xls1,
                                                      p1_asrc, p1_adst, p1_b, p1_sel, scr1, N_NODES);
  topk_count<<<dim3(cdiv(N_NODES, 256), cdiv(N_NODES, TK_CHUNK)), b256, 0, stream>>>(scr1, rank1, N_NODES);
  topk_assign<<<cdiv(N_NODES, 256), b256, 0, stream>>>(rank1, newid1, perm1, N_NODES, K1N);
  col_pool<<<128, b256, 0, stream>>>(h1, perm1, scr1, K1N, HHD, x1max, x1sum);

  // ---- CSR2 + Stage 2 (A = h1 rows gathered via perm1, scaled by scr1) ----
  fill_i32<<<cdiv(30000, 256), b256, 0, stream>>>(deg2, 0, 30000);  // deg2 + rank2
  deg_count<<<cdiv(E2, 256), b256, 0, stream>>>(src, dst, newid1, deg2, K1N);
  scan_excl<<<1, 1024, 0, stream>>>(deg2, rowptr2, deg2, K1N);
  csr_scatter<<<cdiv(E2, 256), b256, 0, stream>>>(src, dst, newid1, deg2, csr_s2, K1N);

  {
    int aBlocks = cdiv((long long)K1N * HHD / 4, 256);
    int wBlocks = cdiv(2 * HIDD * HHD, 256);
    conv_fused<<<aBlocks + wBlocks, b256, 0, stream>>>(
        h1, perm1, scr1, ah2, al2, K1N, HHD, g2_wl, g2_wr, wh2, wl2, HIDD, aBlocks);
  }
  gemm_bf16x3<64><<<dim3(2 * HIDD / 64, cdiv(K1N, 64)), b256, 0, stream>>>(
      ah2, al2, wh2, wl2, xl2, xr2, K1N, HHD, HIDD);
  gat2_fused<<<cdiv((long long)K1N * 64, 256), b256, 0, stream>>>(
      rowptr2, csr_s2, xl2, xr2, g2_att, g2_b, p2_w, h2, xls2, K1N);

  // ---- Pool 2 ----
  pool_score<<<cdiv(K1N, 256), b256, 0, stream>>>(rowptr2, csr_s2, xls2,
                                                  p2_asrc, p2_adst, p2_b, p2_sel, scr2, K1N);
  topk_count<<<dim3(cdiv(K1N, 256), cdiv(K1N, TK_CHUNK)), b256, 0, stream>>>(scr2, rank2, K1N);
  topk_assign<<<cdiv(K1N, 256), b256, 0, stream>>>(rank2, newid2, perm2, K1N, K2N);
  col_pool<<<128, b256, 0, stream>>>(h2, perm2, scr2, K2N, HIDD, g2max, g2sum);

  // ---- MLP head ----
  mlp_l1<<<32, b256, 0, stream>>>(pools, l1_w, l1_b, z1);
  mlp_tail<<<1, b256, 0, stream>>>(z1, l2_w, l2_b, l3_w, l3_b, l4_w, l4_b, (float*)d_out);
}

// Round 8
// 550.361 us; speedup vs baseline: 1.3398x; 1.0992x over previous
//
#include <hip/hip_runtime.h>
#include <math.h>

#define N_NODES 20000
#define E_EDGES 320000
#define DIN     256
#define HHD     512
#define HIDD    64
#define NHEADS  8
#define K1N     15000
#define K2N     11250

typedef unsigned short u16;
typedef __attribute__((ext_vector_type(8))) short bf16x8;
typedef __attribute__((ext_vector_type(4))) float f32x4;

static inline int cdiv(long long a, long long b) { return (int)((a + b - 1) / b); }

__device__ __forceinline__ void atomicMaxF(float* addr, float val) {
  int* ai = (int*)addr;
  int old = __float_as_int(*addr);
  while (__int_as_float(old) < val) {
    int assumed = old;
    old = atomicCAS(ai, assumed, __float_as_int(val));
    if (old == assumed) break;
  }
}

__device__ __forceinline__ u16 f2bf(float x) {   // RNE f32 -> bf16 bits
  unsigned u = __float_as_uint(x);
  return (u16)((u + 0x7FFFu + ((u >> 16) & 1u)) >> 16);
}
__device__ __forceinline__ float bfval(u16 b) { return __uint_as_float(((unsigned)b) << 16); }

// deg1=0, rank1=0, pools[1152]: [-inf x512, 0 x512, -inf x64, 0 x64]
__global__ void init_all(int* deg1, int* rank1, float* pools) {
  int i = blockIdx.x * blockDim.x + threadIdx.x;
  if (i < N_NODES) deg1[i] = 0;
  else if (i < 2 * N_NODES) rank1[i - N_NODES] = 0;
  else {
    int idx = i - 2 * N_NODES;
    if (idx < 1152)
      pools[idx] = (idx < 512 || (idx >= 1024 && idx < 1088)) ? -INFINITY : 0.f;
  }
}

// ---------------- fused bf16 hi/lo split conversion (A-part + W-part in one launch) ----------------
__global__ void conv_fused(const float* __restrict__ A, const int* __restrict__ perm,
                           const float* __restrict__ scalev,
                           u16* __restrict__ ah, u16* __restrict__ al, int M, int K,
                           const float* __restrict__ w1, const float* __restrict__ w2,
                           u16* __restrict__ wh, u16* __restrict__ wl, int ncHalf,
                           int aBlocks) {
  if ((int)blockIdx.x < aBlocks) {
    long long i = (long long)blockIdx.x * blockDim.x + threadIdx.x;
    long long e0 = i * 4;
    if (e0 >= (long long)M * K) return;
    int row = (int)(e0 / K), col = (int)(e0 % K);
    int ar = perm ? perm[row] : row;
    float4 v = *(const float4*)(A + (size_t)ar * K + col);
    if (scalev) { float s = scalev[ar]; v.x *= s; v.y *= s; v.z *= s; v.w *= s; }
    u16 h0 = f2bf(v.x), h1 = f2bf(v.y), h2 = f2bf(v.z), h3 = f2bf(v.w);
    u16 l0 = f2bf(v.x - bfval(h0)), l1 = f2bf(v.y - bfval(h1));
    u16 l2 = f2bf(v.z - bfval(h2)), l3 = f2bf(v.w - bfval(h3));
    uint2 hp, lp;
    hp.x = (unsigned)h0 | ((unsigned)h1 << 16); hp.y = (unsigned)h2 | ((unsigned)h3 << 16);
    lp.x = (unsigned)l0 | ((unsigned)l1 << 16); lp.y = (unsigned)l2 | ((unsigned)l3 << 16);
    *(uint2*)(ah + e0) = hp;
    *(uint2*)(al + e0) = lp;
  } else {
    int i = (blockIdx.x - aBlocks) * blockDim.x + threadIdx.x;
    int NT = 2 * ncHalf;
    if (i >= NT * K) return;
    int n = i % NT, k = i / NT;
    float v = (n < ncHalf) ? w1[(size_t)k * ncHalf + n] : w2[(size_t)k * ncHalf + (n - ncHalf)];
    u16 h = f2bf(v);
    u16 l = f2bf(v - bfval(h));
    wh[(size_t)n * K + k] = h;
    wl[(size_t)n * K + k] = l;
  }
}

// ---------------- split-bf16 MFMA GEMM: C = A @ [W1|W2], 3-product compensation ----------------
template<int BT>
__global__ __launch_bounds__(256) void gemm_bf16x3(const u16* __restrict__ ah,
                                                   const u16* __restrict__ al,
                                                   const u16* __restrict__ wh,
                                                   const u16* __restrict__ wl,
                                                   float* __restrict__ c1,
                                                   float* __restrict__ c2,
                                                   int M, int K, int ncHalf) {
  constexpr int F = BT / 32;
  __shared__ u16 Ah[BT][40], Al[BT][40], Bh[BT][40], Bl[BT][40];
  int tid = threadIdx.x;
  int lane = tid & 63, wid = tid >> 6;
  int wr = (wid >> 1) * (BT / 2), wc = (wid & 1) * (BT / 2);
  int brow = blockIdx.y * BT, bcol = blockIdx.x * BT;
  int fr = lane & 15, kg = lane >> 4;
  f32x4 acc[F][F];
#pragma unroll
  for (int i = 0; i < F; i++)
#pragma unroll
    for (int j = 0; j < F; j++) acc[i][j] = (f32x4){0.f, 0.f, 0.f, 0.f};

  for (int k0 = 0; k0 < K; k0 += 32) {
    constexpr int ITER = (BT * 32) / (256 * 8);
#pragma unroll
    for (int i = 0; i < ITER; i++) {
      int pos = tid + i * 256;
      int row = pos >> 2;
      int kc = (pos & 3) * 8;
      int gr = brow + row;
      float4 z = make_float4(0.f, 0.f, 0.f, 0.f);
      float4 vah = (gr < M) ? *(const float4*)(ah + (size_t)gr * K + k0 + kc) : z;
      float4 val = (gr < M) ? *(const float4*)(al + (size_t)gr * K + k0 + kc) : z;
      *(float4*)(&Ah[row][kc]) = vah;
      *(float4*)(&Al[row][kc]) = val;
      int gn = bcol + row;
      *(float4*)(&Bh[row][kc]) = *(const float4*)(wh + (size_t)gn * K + k0 + kc);
      *(float4*)(&Bl[row][kc]) = *(const float4*)(wl + (size_t)gn * K + k0 + kc);
    }
    __syncthreads();
    bf16x8 fa_h[F], fa_l[F], fb_h[F], fb_l[F];
#pragma unroll
    for (int t = 0; t < F; t++) {
      fa_h[t] = *(const bf16x8*)(&Ah[wr + t * 16 + fr][kg * 8]);
      fa_l[t] = *(const bf16x8*)(&Al[wr + t * 16 + fr][kg * 8]);
      fb_h[t] = *(const bf16x8*)(&Bh[wc + t * 16 + fr][kg * 8]);
      fb_l[t] = *(const bf16x8*)(&Bl[wc + t * 16 + fr][kg * 8]);
    }
#pragma unroll
    for (int i = 0; i < F; i++)
#pragma unroll
      for (int j = 0; j < F; j++) {
        acc[i][j] = __builtin_amdgcn_mfma_f32_16x16x32_bf16(fa_h[i], fb_h[j], acc[i][j], 0, 0, 0);
        acc[i][j] = __builtin_amdgcn_mfma_f32_16x16x32_bf16(fa_h[i], fb_l[j], acc[i][j], 0, 0, 0);
        acc[i][j] = __builtin_amdgcn_mfma_f32_16x16x32_bf16(fa_l[i], fb_h[j], acc[i][j], 0, 0, 0);
      }
    __syncthreads();
  }
#pragma unroll
  for (int i = 0; i < F; i++) {
    int r0 = brow + wr + i * 16 + kg * 4;
#pragma unroll
    for (int j = 0; j < F; j++) {
      int cg = bcol + wc + j * 16 + fr;
      float* cp = (cg < ncHalf) ? c1 : c2;
      int cc = (cg < ncHalf) ? cg : cg - ncHalf;
#pragma unroll
      for (int r = 0; r < 4; r++) {
        int gr = r0 + r;
        if (gr < M) cp[(size_t)gr * ncHalf + cc] = acc[i][j][r];
      }
    }
  }
}

// ---------------- CSR construction (stores mapped source id directly) ----------------
__global__ void deg_count(const int* __restrict__ src, const int* __restrict__ dst,
                          const int* __restrict__ newid, int* __restrict__ deg,
                          int nloops) {
  int i = blockIdx.x * blockDim.x + threadIdx.x;
  if (i >= E_EDGES + nloops) return;
  int d;
  if (i < E_EDGES) {
    if (newid) {
      int s = newid[src[i]]; d = newid[dst[i]];
      if (s < 0 || d < 0) return;
    } else d = dst[i];
  } else d = i - E_EDGES;
  atomicAdd(&deg[d], 1);
}

// shuffle-based single-block exclusive scan; cursor may alias deg.
__global__ __launch_bounds__(1024) void scan_excl(const int* deg, int* rowptr,
                                                  int* cursor, int n) {
  __shared__ int wsum[16];
  __shared__ int carry;
  int tid = threadIdx.x, lane = tid & 63, wid = tid >> 6;
  if (tid == 0) { carry = 0; rowptr[0] = 0; }
  __syncthreads();
  for (int base = 0; base < n; base += 1024) {
    int v = (base + tid < n) ? deg[base + tid] : 0;
    int s = v;
#pragma unroll
    for (int off = 1; off < 64; off <<= 1) {
      int t = __shfl_up(s, off);
      if (lane >= off) s += t;
    }
    if (lane == 63) wsum[wid] = s;
    __syncthreads();
    if (wid == 0) {
      int w = (lane < 16) ? wsum[lane] : 0;
#pragma unroll
      for (int off = 1; off < 16; off <<= 1) {
        int t = __shfl_up(w, off);
        if (lane >= off) w += t;
      }
      if (lane < 16) wsum[lane] = w;
    }
    __syncthreads();
    int incl = s + (wid > 0 ? wsum[wid - 1] : 0) + carry;
    if (base + tid < n) { rowptr[base + tid + 1] = incl; cursor[base + tid] = incl - v; }
    __syncthreads();
    if (tid == 1023) carry = incl;
    __syncthreads();
  }
}

__global__ void csr_scatter(const int* __restrict__ src, const int* __restrict__ dst,
                            const int* __restrict__ newid, int* __restrict__ cursor,
                            int* __restrict__ csr_s, int nloops) {
  int i = blockIdx.x * blockDim.x + threadIdx.x;
  if (i >= E_EDGES + nloops) return;
  int s, d;
  if (i < E_EDGES) {
    s = src[i]; d = dst[i];
    if (newid) {
      s = newid[s]; d = newid[d];
      if (s < 0 || d < 0) return;
    }
  } else s = d = i - E_EDGES;
  int pos = atomicAdd(&cursor[d], 1);
  csr_s[pos] = s;
}

// ---------------- Stage 1 fused GAT, 4-deep software pipeline ----------------
__global__ __launch_bounds__(256) void gat1_fused(const int* __restrict__ rowptr,
                                                  const int* __restrict__ csr_s,
                                                  const float* __restrict__ xl,
                                                  const float* __restrict__ xr,
                                                  const float* __restrict__ att,
                                                  const float* __restrict__ bias,
                                                  const float* __restrict__ pw,
                                                  float* __restrict__ out,
                                                  float* __restrict__ xls) {
  int lane = threadIdx.x & 63;
  long long t = (long long)blockIdx.x * blockDim.x + threadIdx.x;
  int d = (int)(t >> 6);
  if (d >= N_NODES) return;
  int base = lane * 8;
  float4 a0 = *(const float4*)(att + base);
  float4 a1 = *(const float4*)(att + base + 4);
  const float* xrp = xr + (size_t)d * HHD + base;
  float4 r0 = *(const float4*)(xrp);
  float4 r1 = *(const float4*)(xrp + 4);
  float m = -INFINITY, den = 0.f;
  float acc[8] = {0.f, 0.f, 0.f, 0.f, 0.f, 0.f, 0.f, 0.f};
  int b0 = rowptr[d];
  int cnt = rowptr[d + 1] - b0;
  const int* sp = csr_s + b0;

  auto online = [&](float4 v0, float4 v1) {
    float p, tv;
    tv = v0.x + r0.x; tv = tv > 0.f ? tv : 0.2f * tv; p  = tv * a0.x;
    tv = v0.y + r0.y; tv = tv > 0.f ? tv : 0.2f * tv; p += tv * a0.y;
    tv = v0.z + r0.z; tv = tv > 0.f ? tv : 0.2f * tv; p += tv * a0.z;
    tv = v0.w + r0.w; tv = tv > 0.f ? tv : 0.2f * tv; p += tv * a0.w;
    tv = v1.x + r1.x; tv = tv > 0.f ? tv : 0.2f * tv; p += tv * a1.x;
    tv = v1.y + r1.y; tv = tv > 0.f ? tv : 0.2f * tv; p += tv * a1.y;
    tv = v1.z + r1.z; tv = tv > 0.f ? tv : 0.2f * tv; p += tv * a1.z;
    tv = v1.w + r1.w; tv = tv > 0.f ? tv : 0.2f * tv; p += tv * a1.w;
    p += __shfl_xor(p, 1); p += __shfl_xor(p, 2); p += __shfl_xor(p, 4);
    float nm = fmaxf(m, p);
    float w  = __expf(p - nm);
    float sc = __expf(m - nm);
    den = den * sc + w;
    acc[0] = acc[0] * sc + w * v0.x;
    acc[1] = acc[1] * sc + w * v0.y;
    acc[2] = acc[2] * sc + w * v0.z;
    acc[3] = acc[3] * sc + w * v0.w;
    acc[4] = acc[4] * sc + w * v1.x;
    acc[5] = acc[5] * sc + w * v1.y;
    acc[6] = acc[6] * sc + w * v1.z;
    acc[7] = acc[7] * sc + w * v1.w;
    m = nm;
  };

  float4 A0, A1, B0, B1, C0, C1, D0, D1;
  float4 zz = make_float4(0.f, 0.f, 0.f, 0.f);
  {
    const float* p0 = xl + (size_t)sp[0] * HHD + base;
    A0 = *(const float4*)p0; A1 = *(const float4*)(p0 + 4);
  }
  B0 = zz; B1 = zz; C0 = zz; C1 = zz; D0 = zz; D1 = zz;
  if (cnt > 1) { const float* p = xl + (size_t)sp[1] * HHD + base; B0 = *(const float4*)p; B1 = *(const float4*)(p + 4); }
  if (cnt > 2) { const float* p = xl + (size_t)sp[2] * HHD + base; C0 = *(const float4*)p; C1 = *(const float4*)(p + 4); }
  if (cnt > 3) { const float* p = xl + (size_t)sp[3] * HHD + base; D0 = *(const float4*)p; D1 = *(const float4*)(p + 4); }
  int j = 0;
  for (; j + 4 <= cnt; j += 4) {
    float4 v0 = A0, v1 = A1;
    if (j + 4 < cnt) { const float* p = xl + (size_t)sp[j + 4] * HHD + base; A0 = *(const float4*)p; A1 = *(const float4*)(p + 4); }
    online(v0, v1);
    v0 = B0; v1 = B1;
    if (j + 5 < cnt) { const float* p = xl + (size_t)sp[j + 5] * HHD + base; B0 = *(const float4*)p; B1 = *(const float4*)(p + 4); }
    online(v0, v1);
    v0 = C0; v1 = C1;
    if (j + 6 < cnt) { const float* p = xl + (size_t)sp[j + 6] * HHD + base; C0 = *(const float4*)p; C1 = *(const float4*)(p + 4); }
    online(v0, v1);
    v0 = D0; v1 = D1;
    if (j + 7 < cnt) { const float* p = xl + (size_t)sp[j + 7] * HHD + base; D0 = *(const float4*)p; D1 = *(const float4*)(p + 4); }
    online(v0, v1);
  }
  if (j < cnt) {
    online(A0, A1);
    if (j + 1 < cnt) {
      online(B0, B1);
      if (j + 2 < cnt) online(C0, C1);
    }
  }

  float inv = 1.f / den;
  float4 b0v = *(const float4*)(bias + base);
  float4 b1v = *(const float4*)(bias + base + 4);
  float o[8];
  o[0] = acc[0] * inv + b0v.x; o[1] = acc[1] * inv + b0v.y;
  o[2] = acc[2] * inv + b0v.z; o[3] = acc[3] * inv + b0v.w;
  o[4] = acc[4] * inv + b1v.x; o[5] = acc[5] * inv + b1v.y;
  o[6] = acc[6] * inv + b1v.z; o[7] = acc[7] * inv + b1v.w;
#pragma unroll
  for (int k = 0; k < 8; k++) o[k] = o[k] > 0.f ? o[k] : 0.f;
  float* op = out + (size_t)d * HHD + base;
  *(float4*)(op)     = make_float4(o[0], o[1], o[2], o[3]);
  *(float4*)(op + 4) = make_float4(o[4], o[5], o[6], o[7]);
  float4 w0 = *(const float4*)(pw + base);
  float4 w1 = *(const float4*)(pw + base + 4);
  float sdot = o[0]*w0.x + o[1]*w0.y + o[2]*w0.z + o[3]*w0.w
             + o[4]*w1.x + o[5]*w1.y + o[6]*w1.z + o[7]*w1.w;
#pragma unroll
  for (int off = 32; off > 0; off >>= 1) sdot += __shfl_xor(sdot, off);
  if (lane == 0) xls[d] = sdot;
}

// ---------------- Stage 2 fused GAT, 4-deep pipeline ----------------
__global__ __launch_bounds__(256) void gat2_fused(const int* __restrict__ rowptr,
                                                  const int* __restrict__ csr_s,
                                                  const float* __restrict__ xl,
                                                  const float* __restrict__ xr,
                                                  const float* __restrict__ att,
                                                  const float* __restrict__ bias,
                                                  const float* __restrict__ pw,
                                                  float* __restrict__ out,
                                                  float* __restrict__ xls, int n) {
  int lane = threadIdx.x & 63;
  long long t = (long long)blockIdx.x * blockDim.x + threadIdx.x;
  int d = (int)(t >> 6);
  if (d >= n) return;
  float av = att[lane];
  float rr = xr[(size_t)d * HIDD + lane];
  float m = -INFINITY, den = 0.f, acc = 0.f;
  int b0 = rowptr[d];
  int cnt = rowptr[d + 1] - b0;
  const int* sp = csr_s + b0;

  auto online = [&](float v) {
    float tv = v + rr; tv = tv > 0.f ? tv : 0.2f * tv;
    float p = tv * av;
#pragma unroll
    for (int off = 32; off > 0; off >>= 1) p += __shfl_xor(p, off);
    float nm = fmaxf(m, p);
    float w  = __expf(p - nm);
    float sc = __expf(m - nm);
    den = den * sc + w;
    acc = acc * sc + w * v;
    m = nm;
  };

  float vA = xl[(size_t)sp[0] * HIDD + lane];
  float vB = (cnt > 1) ? xl[(size_t)sp[1] * HIDD + lane] : 0.f;
  float vC = (cnt > 2) ? xl[(size_t)sp[2] * HIDD + lane] : 0.f;
  float vD = (cnt > 3) ? xl[(size_t)sp[3] * HIDD + lane] : 0.f;
  int j = 0;
  for (; j + 4 <= cnt; j += 4) {
    float v = vA;
    if (j + 4 < cnt) vA = xl[(size_t)sp[j + 4] * HIDD + lane];
    online(v);
    v = vB;
    if (j + 5 < cnt) vB = xl[(size_t)sp[j + 5] * HIDD + lane];
    online(v);
    v = vC;
    if (j + 6 < cnt) vC = xl[(size_t)sp[j + 6] * HIDD + lane];
    online(v);
    v = vD;
    if (j + 7 < cnt) vD = xl[(size_t)sp[j + 7] * HIDD + lane];
    online(v);
  }
  if (j < cnt) {
    online(vA);
    if (j + 1 < cnt) {
      online(vB);
      if (j + 2 < cnt) online(vC);
    }
  }

  float o = acc / den + bias[lane];
  o = o > 0.f ? o : 0.f;
  out[(size_t)d * HIDD + lane] = o;
  float sdot = o * pw[lane];
#pragma unroll
  for (int off = 32; off > 0; off >>= 1) sdot += __shfl_xor(sdot, off);
  if (lane == 0) xls[d] = sdot;
}

// ---------------- pool scoring: online softmax + tanh, 4-deep prefetch ----------------
__global__ __launch_bounds__(256) void pool_score(const int* __restrict__ rowptr,
                                                  const int* __restrict__ csr_s,
                                                  const float* __restrict__ xls,
                                                  const float* __restrict__ asrc,
                                                  const float* __restrict__ adst,
                                                  const float* __restrict__ bias,
                                                  const float* __restrict__ sel,
                                                  float* __restrict__ score, int n) {
  int d = blockIdx.x * blockDim.x + threadIdx.x;
  if (d >= n) return;
  float as = asrc[0], ad = adst[0];
  float ar = xls[d] * ad;
  int b0 = rowptr[d];
  int cnt = rowptr[d + 1] - b0;
  const int* sp = csr_s + b0;
  float m = -INFINITY, den = 0.f, num = 0.f;
  auto upd = [&](float xs) {
    float e = xs * as + ar;
    e = e > 0.f ? e : 0.2f * e;
    float nm = fmaxf(m, e);
    float scv = __expf(m - nm);
    float ex = __expf(e - nm);
    den = den * scv + ex;
    num = num * scv + ex * xs;
    m = nm;
  };
  float xA = xls[sp[0]];
  float xB = (cnt > 1) ? xls[sp[1]] : 0.f;
  float xC = (cnt > 2) ? xls[sp[2]] : 0.f;
  float xD = (cnt > 3) ? xls[sp[3]] : 0.f;
  int j = 0;
  for (; j + 4 <= cnt; j += 4) {
    float x1 = xA;
    if (j + 4 < cnt) xA = xls[sp[j + 4]];
    upd(x1);
    float x2 = xB;
    if (j + 5 < cnt) xB = xls[sp[j + 5]];
    upd(x2);
    float x3 = xC;
    if (j + 6 < cnt) xC = xls[sp[j + 6]];
    upd(x3);
    float x4 = xD;
    if (j + 7 < cnt) xD = xls[sp[j + 7]];
    upd(x4);
  }
  if (j < cnt) {
    upd(xA);
    if (j + 1 < cnt) {
      upd(xB);
      if (j + 2 < cnt) upd(xC);
    }
  }
  float attn = num / den + bias[0];
  float sv = sel[0];
  score[d] = tanhf(attn * sv / fabsf(sv));
}

// ---------------- top-k via 2D-grid rank counting (+optional zero-fill of zbuf) ----------------
#define TK_CHUNK 512
__global__ __launch_bounds__(256) void topk_count(const float* __restrict__ score,
                                                  int* __restrict__ rank, int n,
                                                  int* __restrict__ zbuf, int zn) {
  __shared__ float sc[TK_CHUNK];
  if (zbuf) {
    long long fid = ((long long)blockIdx.y * gridDim.x + blockIdx.x) * 256 + threadIdx.x;
    if (fid < zn) zbuf[fid] = 0;
  }
  int i = blockIdx.x * 256 + threadIdx.x;
  int base = blockIdx.y * TK_CHUNK;
  int cnt = min(TK_CHUNK, n - base);
  for (int j = threadIdx.x; j < cnt; j += 256) sc[j] = score[base + j];
  __syncthreads();
  if (i >= n) return;
  float si = score[i];
  int r = 0;
  for (int j = 0; j < cnt; j++) {
    float sj = sc[j];
    r += (sj > si) || ((sj == si) && ((base + j) < i));
  }
  if (r) atomicAdd(&rank[i], r);
}

__global__ void topk_assign(const int* __restrict__ rank, int* __restrict__ newid,
                            int* __restrict__ perm, int n, int k) {
  int i = blockIdx.x * blockDim.x + threadIdx.x;
  if (i < n) {
    int r = rank[i];
    newid[i] = (r < k) ? r : -1;
    if (r < k) perm[r] = i;
  }
}

// stage-1 column pool fused with stage-2 A-conversion (+W2 conversion in extra blocks)
__global__ __launch_bounds__(256) void col_pool_conv(const float* __restrict__ X,
                                                     const int* __restrict__ perm,
                                                     const float* __restrict__ scalev,
                                                     float* __restrict__ omax,
                                                     float* __restrict__ osum,
                                                     u16* __restrict__ ah, u16* __restrict__ al,
                                                     const float* __restrict__ w1,
                                                     const float* __restrict__ w2,
                                                     u16* __restrict__ wh, u16* __restrict__ wl,
                                                     int cpBlocks) {
  int tid = threadIdx.x;
  if ((int)blockIdx.x < cpBlocks) {
    float mx[2] = {-INFINITY, -INFINITY};
    float sm[2] = {0.f, 0.f};
    int rpb = (K1N + cpBlocks - 1) / cpBlocks;
    int rbeg = blockIdx.x * rpb;
    int rend = min(K1N, rbeg + rpb);
    for (int r = rbeg; r < rend; r++) {
      int orow = perm[r];
      float sc = scalev[orow];
      const float* row = X + (size_t)orow * HHD;
#pragma unroll
      for (int sg = 0; sg < 2; sg++) {
        int c = sg * 256 + tid;
        float v = row[c] * sc;
        mx[sg] = fmaxf(mx[sg], v);
        sm[sg] += v;
        u16 h = f2bf(v);
        u16 l = f2bf(v - bfval(h));
        ah[(size_t)r * HHD + c] = h;
        al[(size_t)r * HHD + c] = l;
      }
    }
    if (rbeg < rend) {
#pragma unroll
      for (int sg = 0; sg < 2; sg++) {
        int c = sg * 256 + tid;
        atomicMaxF(&omax[c], mx[sg]);
        atomicAdd(&osum[c], sm[sg]);
      }
    }
  } else {
    // W2 conversion: [HHD, HIDD] x2 -> wh/wl [2*HIDD][HHD]
    int i = (blockIdx.x - cpBlocks) * 256 + tid;
    const int NT = 2 * HIDD;
    if (i >= NT * HHD) return;
    int n = i % NT, k = i / NT;
    float v = (n < HIDD) ? w1[(size_t)k * HIDD + n] : w2[(size_t)k * HIDD + (n - HIDD)];
    u16 h = f2bf(v);
    u16 l = f2bf(v - bfval(h));
    wh[(size_t)n * HHD + k] = h;
    wl[(size_t)n * HHD + k] = l;
  }
}

// plain column pool (stage 2)
__global__ __launch_bounds__(256) void col_pool(const float* __restrict__ X,
                                                const int* __restrict__ perm,
                                                const float* __restrict__ scalev,
                                                int rows, int C,
                                                float* __restrict__ omax, float* __restrict__ osum) {
  int tid = threadIdx.x;
  float mx = -INFINITY, sm = 0.f;
  int rpb = (rows + gridDim.x - 1) / gridDim.x;
  int rbeg = blockIdx.x * rpb;
  int rend = min(rows, rbeg + rpb);
  for (int r = rbeg; r < rend; r++) {
    int orow = perm[r];
    float sc = scalev[orow];
    int c = tid;
    if (c < C) {
      float v = X[(size_t)orow * C + c] * sc;
      mx = fmaxf(mx, v);
      sm += v;
    }
  }
  if (rbeg < rend && tid < C) {
    atomicMaxF(&omax[tid], mx);
    atomicAdd(&osum[tid], sm);
  }
}

// ---------------- MLP head ----------------
__global__ __launch_bounds__(256) void mlp_l1(const float* __restrict__ pools,
                                              const float* __restrict__ w1,
                                              const float* __restrict__ b1,
                                              float* __restrict__ z1out) {
  __shared__ float z[1024];
  __shared__ float red[16][17];
  int t = threadIdx.x;
  for (int i = t; i < 1024; i += 256) {
    float xv = (i < 512) ? pools[i] : pools[i] * (1.f / K1N);
    float gv = (i < 512) ? pools[1024 + (i & 63)] : pools[1088 + (i & 63)] * (1.f / K2N);
    z[i] = xv + gv;
  }
  __syncthreads();
  int jl = t & 15, ch = t >> 4;
  int j = blockIdx.x * 16 + jl;
  float p = 0.f;
  for (int k = ch * 64; k < ch * 64 + 64; k++) p += z[k] * w1[(size_t)k * 512 + j];
  red[ch][jl] = p;
  __syncthreads();
  if (t < 16) {
    float s = b1[blockIdx.x * 16 + t];
    for (int c = 0; c < 16; c++) s += red[c][t];
    z1out[blockIdx.x * 16 + t] = s > 0.f ? s : 0.f;
  }
}

__global__ __launch_bounds__(256) void mlp_tail(const float* __restrict__ z1,
                                                const float* __restrict__ w2, const float* __restrict__ b2,
                                                const float* __restrict__ w3, const float* __restrict__ b3,
                                                const float* __restrict__ w4, const float* __restrict__ b4,
                                                float* __restrict__ out) {
  __shared__ float z2[256], z3[128], lg[2];
  int t = threadIdx.x;
  {
    float acc = b2[t];
    for (int k = 0; k < 512; k++) acc += z1[k] * w2[(size_t)k * 256 + t];
    z2[t] = acc > 0.f ? acc : 0.f;
  }
  __syncthreads();
  if (t < 128) {
    float acc = b3[t];
    for (int k = 0; k < 256; k++) acc += z2[k] * w3[(size_t)k * 128 + t];
    z3[t] = acc > 0.f ? acc : 0.f;
  }
  __syncthreads();
  if (t < 2) {
    float acc = b4[t];
    for (int k = 0; k < 128; k++) acc += z3[k] * w4[2 * k + t];
    lg[t] = acc;
  }
  __syncthreads();
  if (t == 0) {
    float m = fmaxf(lg[0], lg[1]);
    float e0 = __expf(lg[0] - m), e1 = __expf(lg[1] - m);
    float s = e0 + e1;
    out[0] = lg[0]; out[1] = lg[1];
    out[2] = e0 / s; out[3] = e1 / s;
  }
}

extern "C" void kernel_launch(void* const* d_in, const int* in_sizes, int n_in,
                              void* d_out, int out_size, void* d_ws, size_t ws_size,
                              hipStream_t stream) {
  const float* x       = (const float*)d_in[0];
  const int*   ei      = (const int*)d_in[1];
  const float* g1_wl   = (const float*)d_in[2];
  const float* g1_wr   = (const float*)d_in[3];
  const float* g1_att  = (const float*)d_in[4];
  const float* g1_b    = (const float*)d_in[5];
  const float* p1_w    = (const float*)d_in[6];
  const float* p1_asrc = (const float*)d_in[7];
  const float* p1_adst = (const float*)d_in[8];
  const float* p1_b    = (const float*)d_in[9];
  const float* p1_sel  = (const float*)d_in[10];
  const float* g2_wl   = (const float*)d_in[11];
  const float* g2_wr   = (const float*)d_in[12];
  const float* g2_att  = (const float*)d_in[13];
  const float* g2_b    = (const float*)d_in[14];
  const float* p2_w    = (const float*)d_in[15];
  const float* p2_asrc = (const float*)d_in[16];
  const float* p2_adst = (const float*)d_in[17];
  const float* p2_b    = (const float*)d_in[18];
  const float* p2_sel  = (const float*)d_in[19];
  const float* l1_w    = (const float*)d_in[20];
  const float* l1_b    = (const float*)d_in[21];
  const float* l2_w    = (const float*)d_in[22];
  const float* l2_b    = (const float*)d_in[23];
  const float* l3_w    = (const float*)d_in[24];
  const float* l3_b    = (const float*)d_in[25];
  const float* l4_w    = (const float*)d_in[26];
  const float* l4_b    = (const float*)d_in[27];

  const int* src = ei;
  const int* dst = ei + E_EDGES;

  if (ws_size < (size_t)33440000 * 4) return;
  float* ws  = (float*)d_ws;
  float* xl1 = ws;                 // 10.24M f32; stage-2 bf16 arena after gat1
  float* xr1 = ws + 10240000;      // 10.24M f32; arena2 after gat1
  float* h1  = ws + 20480000;      // 10.24M f32; stage-1 bf16 arena before gat1
  float* aux = ws + 30720000;      // persistent small buffers

  int*   csr_s1   = (int*)aux;               // 340000
  int*   rowptr1  = (int*)(aux + 340000);    // 20001
  int*   deg1     = (int*)(aux + 360064);    // 20000 (deg -> cursor)
  int*   rank1    = (int*)(aux + 380064);    // 20000
  int*   newid1   = (int*)(aux + 400064);    // 20000
  float* xls1     = aux + 420064;            // 20000
  float* scr1     = aux + 440064;            // 20000
  float* pools    = aux + 460064;            // 1152: x1max|x1sum|g2max|g2sum
  float* x1max    = pools;
  float* x1sum    = pools + 512;
  float* g2max    = pools + 1024;
  float* g2sum    = pools + 1088;
  int*   perm1    = (int*)(aux + 461248);    // 20000
  float* z1       = aux + 481248;            // 512

  // stage-1 bf16 hi/lo arena (in h1 region; dead once gat1_fused writes h1)
  u16* ah1 = (u16*)h1;                 // 5,120,000 u16
  u16* al1 = ah1 + 5120000;            // 5,120,000
  u16* wh1 = al1 + 5120000;            // 262,144
  u16* wl1 = wh1 + 262144;             // 262,144

  // stage-2 bf16 hi/lo arena (in xl1 region; xl1 dead after gat1_fused)
  u16* ah2 = (u16*)xl1;                // 7,680,000 u16
  u16* al2 = ah2 + 7680000;            // 7,680,000
  u16* wh2 = al2 + 7680000;            // 65,536
  u16* wl2 = wh2 + 65536;              // 65,536

  float* a2 = xr1;                     // stage-2 f32 arena (xr1 dead after gat1_fused)
  float* xl2      = a2;                      // 960000
  float* xr2      = a2 + 960000;             // 960000
  float* h2       = a2 + 1920000;            // 960000
  int*   csr_s2   = (int*)(a2 + 2880000);    // 335000
  int*   rowptr2  = (int*)(a2 + 3215000);    // 15001
  int*   deg2     = (int*)(a2 + 3230016);    // 15000 (deg2+rank2 contiguous)
  int*   rank2    = (int*)(a2 + 3245016);    // 15000
  int*   newid2   = (int*)(a2 + 3260016);    // 15000
  float* xls2     = a2 + 3275016;            // 15000
  float* scr2     = a2 + 3290016;            // 15000
  int*   perm2    = (int*)(a2 + 3305016);    // 15000

  dim3 b256(256);
  const int E1 = E_EDGES + N_NODES;   // 340000
  const int E2 = E_EDGES + K1N;       // 335000

  // ---- init + CSR1 ----
  init_all<<<cdiv(2 * N_NODES + 1152, 256), b256, 0, stream>>>(deg1, rank1, pools);
  deg_count<<<cdiv(E1, 256), b256, 0, stream>>>(src, dst, nullptr, deg1, N_NODES);
  scan_excl<<<1, 1024, 0, stream>>>(deg1, rowptr1, deg1, N_NODES);
  csr_scatter<<<cdiv(E1, 256), b256, 0, stream>>>(src, dst, nullptr, deg1, csr_s1, N_NODES);

  // ---- Stage 1: conv + bf16-split MFMA GEMM (Wl|Wr) + fused GAT ----
  {
    int aBlocks = cdiv((long long)N_NODES * DIN / 4, 256);
    int wBlocks = cdiv(2 * HHD * DIN, 256);
    conv_fused<<<aBlocks + wBlocks, b256, 0, stream>>>(
        x, nullptr, nullptr, ah1, al1, N_NODES, DIN, g1_wl, g1_wr, wh1, wl1, HHD, aBlocks);
  }
  gemm_bf16x3<128><<<dim3(2 * HHD / 128, cdiv(N_NODES, 128)), b256, 0, stream>>>(
      ah1, al1, wh1, wl1, xl1, xr1, N_NODES, DIN, HHD);
  gat1_fused<<<cdiv((long long)N_NODES * 64, 256), b256, 0, stream>>>(
      rowptr1, csr_s1, xl1, xr1, g1_att, g1_b, p1_w, h1, xls1);

  // ---- Pool 1 (topk_count also zeroes deg2+rank2, which live in dead xr1 region) ----
  pool_score<<<cdiv(N_NODES, 256), b256, 0, stream>>>(rowptr1, csr_s1, xls1,
                                                      p1_asrc, p1_adst, p1_b, p1_sel, scr1, N_NODES);
  topk_count<<<dim3(cdiv(N_NODES, 256), cdiv(N_NODES, TK_CHUNK)), b256, 0, stream>>>(
      scr1, rank1, N_NODES, deg2, 30000);
  topk_assign<<<cdiv(N_NODES, 256), b256, 0, stream>>>(rank1, newid1, perm1, N_NODES, K1N);
  {
    int cpBlocks = 256;
    int wBlocks = cdiv(2 * HIDD * HHD, 256);
    col_pool_conv<<<cpBlocks + wBlocks, b256, 0, stream>>>(
        h1, perm1, scr1, x1max, x1sum, ah2, al2, g2_wl, g2_wr, wh2, wl2, cpBlocks);
  }

  // ---- CSR2 + Stage 2 GEMM + fused GAT ----
  deg_count<<<cdiv(E2, 256), b256, 0, stream>>>(src, dst, newid1, deg2, K1N);
  scan_excl<<<1, 1024, 0, stream>>>(deg2, rowptr2, deg2, K1N);
  csr_scatter<<<cdiv(E2, 256), b256, 0, stream>>>(src, dst, newid1, deg2, csr_s2, K1N);

  gemm_bf16x3<64><<<dim3(2 * HIDD / 64, cdiv(K1N, 64)), b256, 0, stream>>>(
      ah2, al2, wh2, wl2, xl2, xr2, K1N, HHD, HIDD);
  gat2_fused<<<cdiv((long long)K1N * 64, 256), b256, 0, stream>>>(
      rowptr2, csr_s2, xl2, xr2, g2_att, g2_b, p2_w, h2, xls2, K1N);

  // ---- Pool 2 ----
  pool_score<<<cdiv(K1N, 256), b256, 0, stream>>>(rowptr2, csr_s2, xls2,
                                                  p2_asrc, p2_adst, p2_b, p2_sel, scr2, K1N);
  topk_count<<<dim3(cdiv(K1N, 256), cdiv(K1N, TK_CHUNK)), b256, 0, stream>>>(
      scr2, rank2, K1N, nullptr, 0);
  topk_assign<<<cdiv(K1N, 256), b256, 0, stream>>>(rank2, newid2, perm2, K1N, K2N);
  col_pool<<<128, b256, 0, stream>>>(h2, perm2, scr2, K2N, HIDD, g2max, g2sum);

  // ---- MLP head ----
  mlp_l1<<<32, b256, 0, stream>>>(pools, l1_w, l1_b, z1);
  mlp_tail<<<1, b256, 0, stream>>>(z1, l2_w, l2_b, l3_w, l3_b, l4_w, l4_b, (float*)d_out);
}